// Round 1
// baseline (2567.095 us; speedup 1.0000x reference)
//
#include <hip/hip_runtime.h>
#include <hip/hip_bf16.h>

#define BB 8
#define NN 4096
#define EE 131072          // 2^17
#define ENL (EE + NN)      // 135168 edges incl self loops
#define DD 256
#define HH 8
#define HD 2048
#define NPB (BB * NN)      // 32768 nodes total

static __device__ __forceinline__ float bf_lo(unsigned int u) { return __uint_as_float(u << 16); }
static __device__ __forceinline__ float bf_hi(unsigned int u) { return __uint_as_float(u & 0xFFFF0000u); }
static __device__ __forceinline__ unsigned short f2bf(float f) {
    __hip_bfloat16 h = __float2bfloat16(f);
    return *reinterpret_cast<unsigned short*>(&h);
}

// ---------- CSR build ----------
__global__ void k_count(const int* __restrict__ edges, int* __restrict__ deg) {
    int idx = blockIdx.x * 256 + threadIdx.x;      // over B*E
    int b = idx >> 17;
    int e = idx & (EE - 1);
    int dst = edges[b * 2 * EE + EE + e];
    atomicAdd(&deg[b * NN + dst], 1);
}

__global__ void k_scan(const int* __restrict__ deg, int* __restrict__ rowptr, int* __restrict__ cursor) {
    __shared__ int buf[1024];
    int b = blockIdx.x, t = threadIdx.x;
    int base = b * NN;
    int v0 = deg[base + t*4 + 0] + 1;              // +1 self loop
    int v1 = v0 + deg[base + t*4 + 1] + 1;
    int v2 = v1 + deg[base + t*4 + 2] + 1;
    int v3 = v2 + deg[base + t*4 + 3] + 1;
    buf[t] = v3; __syncthreads();
    for (int off = 1; off < 1024; off <<= 1) {
        int x = (t >= off) ? buf[t - off] : 0;
        __syncthreads();
        buf[t] += x;
        __syncthreads();
    }
    int excl = buf[t] - v3;
    int rp = b * (NN + 1);
    if (t == 0) rowptr[rp] = 0;
    rowptr[rp + t*4 + 1] = excl + v0;
    rowptr[rp + t*4 + 2] = excl + v1;
    rowptr[rp + t*4 + 3] = excl + v2;
    rowptr[rp + t*4 + 4] = excl + v3;
    cursor[base + t*4 + 0] = excl;
    cursor[base + t*4 + 1] = excl + v0;
    cursor[base + t*4 + 2] = excl + v1;
    cursor[base + t*4 + 3] = excl + v2;
}

__global__ void k_scatter(const int* __restrict__ edges, int* __restrict__ cursor, int* __restrict__ col) {
    int b = blockIdx.y;
    int idx = blockIdx.x * 256 + threadIdx.x;
    if (idx >= ENL) return;
    int src, dst;
    if (idx < EE) { src = edges[b*2*EE + idx]; dst = edges[b*2*EE + EE + idx]; }
    else { src = dst = idx - EE; }
    int pos = atomicAdd(&cursor[b*NN + dst], 1);
    col[b*ENL + pos] = src;
}

// ---------- weight precompute ----------
// Mk[l][k][h*256+c] = sum_d W[l][h*256+d][k] * linW[l][c][h*256+d]
__global__ void k_prep_M(const float* __restrict__ W, const float* __restrict__ linW, float* __restrict__ Mk) {
    __shared__ float wcol[DD];
    int k = blockIdx.x, h = blockIdx.y, l = blockIdx.z, c = threadIdx.x;
    wcol[c] = W[l*HD*DD + (h*DD + c)*DD + k];
    __syncthreads();
    const float4* lw4 = reinterpret_cast<const float4*>(linW + (size_t)l*DD*HD + (size_t)c*HD + h*DD);
    const float4* wc4 = reinterpret_cast<const float4*>(wcol);
    float acc = 0.f;
    #pragma unroll 8
    for (int d = 0; d < DD/4; ++d) {
        float4 a = wc4[d]; float4 q = lw4[d];
        acc += a.x*q.x + a.y*q.y + a.z*q.z + a.w*q.w;
    }
    Mk[((size_t)l*DD + k)*HD + h*DD + c] = acc;
}

// wsatt[l][h][k] = sum_d att_src[l][h][d]*W[l][h*256+d][k]; wdatt likewise
__global__ void k_prep_att(const float* __restrict__ W, const float* __restrict__ asrc, const float* __restrict__ adst,
                           float* __restrict__ wsatt, float* __restrict__ wdatt) {
    int h = blockIdx.x, l = blockIdx.y, k = threadIdx.x;
    float accs = 0.f, accd = 0.f;
    for (int d = 0; d < DD; ++d) {
        float w = W[l*HD*DD + (h*DD + d)*DD + k];
        accs += asrc[(l*HH + h)*DD + d] * w;
        accd += adst[(l*HH + h)*DD + d] * w;
    }
    wsatt[(l*HH + h)*DD + k] = accs;
    wdatt[(l*HH + h)*DD + k] = accd;
}

// bias2[l][c] = lin_b[l][c] + sum_o gat_bias[l][o]*linW[l][c][o]
__global__ void k_prep_bias(const float* __restrict__ gbias, const float* __restrict__ linW,
                            const float* __restrict__ linb, float* __restrict__ bias2) {
    int l = blockIdx.x, c = threadIdx.x;
    float acc = linb[l*DD + c];
    const float4* g4 = reinterpret_cast<const float4*>(gbias + l*HD);
    const float4* w4 = reinterpret_cast<const float4*>(linW + (size_t)l*DD*HD + (size_t)c*HD);
    for (int o = 0; o < HD/4; ++o) {
        float4 g = g4[o]; float4 w = w4[o];
        acc += g.x*w.x + g.y*w.y + g.z*w.z + g.w*w.w;
    }
    bias2[l*DD + c] = acc;
}

// ---------- z = X @ Mk (f32 SIMT, bf16 output) ----------
__global__ __launch_bounds__(256) void k_gemm_z(const float* __restrict__ A, const float* __restrict__ Bm,
                                                unsigned int* __restrict__ Z) {
    __shared__ float As[64][68];
    __shared__ float Bs[32][68];
    int tid = threadIdx.x;
    int tx = tid & 15, ty = tid >> 4;
    int m0 = blockIdx.y * 64, n0 = blockIdx.x * 64;
    float acc[4][4] = {};
    for (int kt = 0; kt < 256; kt += 32) {
        #pragma unroll
        for (int i = 0; i < 2; ++i) {
            int f = tid + i*256;
            int row = f >> 3, c4 = f & 7;
            float4 a = *reinterpret_cast<const float4*>(&A[(size_t)(m0 + row)*256 + kt + c4*4]);
            *reinterpret_cast<float4*>(&As[row][c4*4]) = a;
        }
        #pragma unroll
        for (int i = 0; i < 2; ++i) {
            int f = tid + i*256;
            int kr = f >> 4, c4 = f & 15;
            float4 q = *reinterpret_cast<const float4*>(&Bm[(size_t)(kt + kr)*HD + n0 + c4*4]);
            *reinterpret_cast<float4*>(&Bs[kr][c4*4]) = q;
        }
        __syncthreads();
        #pragma unroll
        for (int k = 0; k < 32; ++k) {
            float4 b4 = *reinterpret_cast<const float4*>(&Bs[k][tx*4]);
            #pragma unroll
            for (int i = 0; i < 4; ++i) {
                float a = As[ty*4 + i][k];
                acc[i][0] += a * b4.x; acc[i][1] += a * b4.y;
                acc[i][2] += a * b4.z; acc[i][3] += a * b4.w;
            }
        }
        __syncthreads();
    }
    #pragma unroll
    for (int i = 0; i < 4; ++i) {
        int r = m0 + ty*4 + i;
        unsigned int lo = ((unsigned)f2bf(acc[i][1]) << 16) | f2bf(acc[i][0]);
        unsigned int hi = ((unsigned)f2bf(acc[i][3]) << 16) | f2bf(acc[i][2]);
        uint2 val = make_uint2(lo, hi);
        *reinterpret_cast<uint2*>(&Z[(size_t)r*1024 + n0/2 + tx*2]) = val;
    }
}

// ---------- attention scores a_s, a_d ----------
__global__ void k_attn_scores(const float* __restrict__ X, const float* __restrict__ ws_l, const float* __restrict__ wd_l,
                              float* __restrict__ a_s, float* __restrict__ a_d) {
    int tid = threadIdx.x;
    int g = blockIdx.x * 16 + (tid >> 4);
    int o = tid & 15;
    int h = o & 7;
    const float* wt = ((o < 8) ? ws_l : wd_l) + h*DD;
    const float4* x4 = reinterpret_cast<const float4*>(X + (size_t)g*DD);
    const float4* w4 = reinterpret_cast<const float4*>(wt);
    float acc = 0.f;
    #pragma unroll 8
    for (int k = 0; k < 64; ++k) {
        float4 x = x4[k], w = w4[k];
        acc += x.x*w.x + x.y*w.y + x.z*w.z + x.w*w.w;
    }
    if (o < 8) a_s[g*8 + h] = acc; else a_d[g*8 + h] = acc;
}

// ---------- aggregation + bias + LN + residual + relu (one wave per dst node) ----------
__global__ __launch_bounds__(256) void k_agg(const int* __restrict__ rowptr, const int* __restrict__ col,
                                             const float* __restrict__ a_s, const float* __restrict__ a_d,
                                             const unsigned int* __restrict__ Z, const float* __restrict__ bias2,
                                             const float* __restrict__ gamma, const float* __restrict__ beta,
                                             const float* __restrict__ res, float* __restrict__ out) {
    int wave = threadIdx.x >> 6;
    int lane = threadIdx.x & 63;
    int g = blockIdx.x * 4 + wave;
    int b = g >> 12, n = g & (NN - 1);
    int rp = rowptr[b*(NN+1) + n], re = rowptr[b*(NN+1) + n + 1];
    const int* cl = col + b*ENL;
    int gb = b * NN;
    int h_idx = lane & 7;
    float a_d_h = a_d[(size_t)g*8 + h_idx];
    float m = -INFINITY, s = 0.f;
    // pass 1: online softmax stats, 8 edges x 8 heads per step
    for (int e0 = rp; e0 < re; e0 += 8) {
        int e = e0 + (lane >> 3);
        bool valid = e < re;
        int src = valid ? cl[e] : 0;
        float v = -INFINITY;
        if (valid) {
            float x = a_s[(size_t)(gb + src)*8 + h_idx] + a_d_h;
            v = (x > 0.f) ? x : 0.2f * x;
        }
        float cm = v;
        cm = fmaxf(cm, __shfl_xor(cm, 8));
        cm = fmaxf(cm, __shfl_xor(cm, 16));
        cm = fmaxf(cm, __shfl_xor(cm, 32));
        float nm = fmaxf(m, cm);
        float t = valid ? __expf(v - nm) : 0.f;
        t += __shfl_xor(t, 8);
        t += __shfl_xor(t, 16);
        t += __shfl_xor(t, 32);
        s = s * __expf(m - nm) + t;
        m = nm;
    }
    float rinv = 1.f / (s + 1e-16f);
    float mAll[8], rAll[8], adAll[8];
    #pragma unroll
    for (int hh = 0; hh < 8; ++hh) {
        mAll[hh]  = __shfl(m, hh);
        rAll[hh]  = __shfl(rinv, hh);
        adAll[hh] = __shfl(a_d_h, hh);
    }
    // pass 2: weighted aggregation of z rows
    float acc0 = 0.f, acc1 = 0.f, acc2 = 0.f, acc3 = 0.f;
    for (int e = rp; e < re; ++e) {
        int src = cl[e];
        const float* asr = a_s + (size_t)(gb + src)*8;
        const unsigned int* zr = Z + (size_t)(gb + src)*1024;
        float w[8];
        #pragma unroll
        for (int hh = 0; hh < 8; ++hh) {
            float x = asr[hh] + adAll[hh];
            x = (x > 0.f) ? x : 0.2f * x;
            w[hh] = __expf(x - mAll[hh]) * rAll[hh];
        }
        #pragma unroll
        for (int hh = 0; hh < 8; ++hh) {
            uint2 u = *reinterpret_cast<const uint2*>(&zr[hh*128 + lane*2]);
            acc0 += w[hh] * bf_lo(u.x);
            acc1 += w[hh] * bf_hi(u.x);
            acc2 += w[hh] * bf_lo(u.y);
            acc3 += w[hh] * bf_hi(u.y);
        }
    }
    // epilogue: +bias2, LayerNorm, +res, relu
    int c = lane * 4;
    float4 b2 = *reinterpret_cast<const float4*>(&bias2[c]);
    float g0 = acc0 + b2.x, g1 = acc1 + b2.y, g2 = acc2 + b2.z, g3 = acc3 + b2.w;
    float sum = g0 + g1 + g2 + g3;
    #pragma unroll
    for (int msk = 1; msk < 64; msk <<= 1) sum += __shfl_xor(sum, msk);
    float mu = sum * (1.f/256.f);
    float d0 = g0-mu, d1 = g1-mu, d2 = g2-mu, d3 = g3-mu;
    float vs = d0*d0 + d1*d1 + d2*d2 + d3*d3;
    #pragma unroll
    for (int msk = 1; msk < 64; msk <<= 1) vs += __shfl_xor(vs, msk);
    float rstd = rsqrtf(vs * (1.f/256.f) + 1e-5f);
    float4 gm = *reinterpret_cast<const float4*>(&gamma[c]);
    float4 bt = *reinterpret_cast<const float4*>(&beta[c]);
    float4 rs = *reinterpret_cast<const float4*>(&res[(size_t)g*256 + c]);
    float o0 = d0*rstd*gm.x + bt.x + rs.x;
    float o1 = d1*rstd*gm.y + bt.y + rs.y;
    float o2 = d2*rstd*gm.z + bt.z + rs.z;
    float o3 = d3*rstd*gm.w + bt.w + rs.w;
    float4 ov = make_float4(fmaxf(o0,0.f), fmaxf(o1,0.f), fmaxf(o2,0.f), fmaxf(o3,0.f));
    *reinterpret_cast<float4*>(&out[(size_t)g*256 + c]) = ov;
}

extern "C" void kernel_launch(void* const* d_in, const int* in_sizes, int n_in,
                              void* d_out, int out_size, void* d_ws, size_t ws_size,
                              hipStream_t stream) {
    const float* emb   = (const float*)d_in[0];
    const int*   edges = (const int*)d_in[1];
    const float* W     = (const float*)d_in[2];
    const float* asrc  = (const float*)d_in[3];
    const float* adst  = (const float*)d_in[4];
    const float* gbias = (const float*)d_in[5];
    const float* linW  = (const float*)d_in[6];
    const float* linb  = (const float*)d_in[7];
    const float* gam   = (const float*)d_in[8];
    const float* bet   = (const float*)d_in[9];
    float* out = (float*)d_out;

    // workspace layout (bytes)
    char* ws = (char*)d_ws;
    unsigned int* Z = (unsigned int*)(ws + 0);             // 134217728 (bf16 z: [32768][2048])
    float* Mk       = (float*)(ws + 134217728);            // 4194304
    float* wsatt    = (float*)(ws + 138412032);            // 16384
    float* wdatt    = (float*)(ws + 138428416);            // 16384
    float* bias2    = (float*)(ws + 138444800);            // 2048
    float* a_s      = (float*)(ws + 138446848);            // 1048576
    float* a_d      = (float*)(ws + 139495424);            // 1048576
    int* deg        = (int*)(ws + 140544000);              // 131072
    int* cursor     = (int*)(ws + 140675072);              // 131072
    int* rowptr     = (int*)(ws + 140806144);              // 131104
    int* colx       = (int*)(ws + 140937248);              // 4325376  -> total ~145.3 MB

    hipMemsetAsync(deg, 0, BB*NN*sizeof(int), stream);
    k_count<<<dim3(BB*EE/256), 256, 0, stream>>>(edges, deg);
    k_scan<<<dim3(BB), 1024, 0, stream>>>(deg, rowptr, cursor);
    k_scatter<<<dim3(ENL/256, BB), 256, 0, stream>>>(edges, cursor, colx);
    k_prep_M<<<dim3(256, 8, 2), 256, 0, stream>>>(W, linW, Mk);
    k_prep_att<<<dim3(8, 2), 256, 0, stream>>>(W, asrc, adst, wsatt, wdatt);
    k_prep_bias<<<dim3(2), 256, 0, stream>>>(gbias, linW, linb, bias2);

    for (int l = 0; l < 2; ++l) {
        const float* X = (l == 0) ? emb : out;
        k_gemm_z<<<dim3(HD/64, NPB/64), 256, 0, stream>>>(X, Mk + (size_t)l*DD*HD, Z);
        k_attn_scores<<<dim3(NPB/16), 256, 0, stream>>>(X, wsatt + l*HH*DD, wdatt + l*HH*DD, a_s, a_d);
        k_agg<<<dim3(NPB/4), 256, 0, stream>>>(rowptr, colx, a_s, a_d, Z, bias2 + l*DD,
                                               gam, bet, X, out);
    }
}

// Round 2
// 1435.725 us; speedup vs baseline: 1.7880x; 1.7880x over previous
//
#include <hip/hip_runtime.h>
#include <hip/hip_bf16.h>

#define BB 8
#define NN 4096
#define EE 131072          // edges per graph
#define ENL (EE + NN)      // + self loops
#define DD 256
#define HH 8
#define HD 2048
#define NPB (BB * NN)      // 32768 nodes total
#define CHUNK 16384        // nodes per y-chunk (4 graphs)

typedef __attribute__((ext_vector_type(8))) short bf16x8;
typedef __attribute__((ext_vector_type(4))) float f32x4;

static __device__ __forceinline__ float bf_lo(unsigned int u) { return __uint_as_float(u << 16); }
static __device__ __forceinline__ float bf_hi(unsigned int u) { return __uint_as_float(u & 0xFFFF0000u); }
static __device__ __forceinline__ unsigned short f2bf(float f) {
    __hip_bfloat16 h = __float2bfloat16(f);
    return *reinterpret_cast<unsigned short*>(&h);
}
static __device__ __forceinline__ unsigned int pack2(float a, float b) {
    return ((unsigned)f2bf(b) << 16) | f2bf(a);
}

// ---------- CSR build ----------
__global__ void k_count(const int* __restrict__ edges, int* __restrict__ deg) {
    int idx = blockIdx.x * 256 + threadIdx.x;
    int b = idx >> 17;
    int e = idx & (EE - 1);
    int dst = edges[b * 2 * EE + EE + e];
    atomicAdd(&deg[b * NN + dst], 1);
}

__global__ void k_scan(const int* __restrict__ deg, int* __restrict__ rowptr, int* __restrict__ cursor) {
    __shared__ int buf[1024];
    int b = blockIdx.x, t = threadIdx.x;
    int base = b * NN;
    int v0 = deg[base + t*4 + 0] + 1;
    int v1 = v0 + deg[base + t*4 + 1] + 1;
    int v2 = v1 + deg[base + t*4 + 2] + 1;
    int v3 = v2 + deg[base + t*4 + 3] + 1;
    buf[t] = v3; __syncthreads();
    for (int off = 1; off < 1024; off <<= 1) {
        int x = (t >= off) ? buf[t - off] : 0;
        __syncthreads();
        buf[t] += x;
        __syncthreads();
    }
    int excl = buf[t] - v3;
    int rp = b * (NN + 1);
    if (t == 0) rowptr[rp] = 0;
    rowptr[rp + t*4 + 1] = excl + v0;
    rowptr[rp + t*4 + 2] = excl + v1;
    rowptr[rp + t*4 + 3] = excl + v2;
    rowptr[rp + t*4 + 4] = excl + v3;
    cursor[base + t*4 + 0] = excl;
    cursor[base + t*4 + 1] = excl + v0;
    cursor[base + t*4 + 2] = excl + v1;
    cursor[base + t*4 + 3] = excl + v2;
}

__global__ void k_scatter(const int* __restrict__ edges, int* __restrict__ cursor, int* __restrict__ col) {
    int b = blockIdx.y;
    int idx = blockIdx.x * 256 + threadIdx.x;
    if (idx >= ENL) return;
    int src, dst;
    if (idx < EE) { src = edges[b*2*EE + idx]; dst = edges[b*2*EE + EE + idx]; }
    else { src = dst = idx - EE; }
    int pos = atomicAdd(&cursor[b*NN + dst], 1);
    col[b*ENL + pos] = src;
}

// ---------- weight precompute ----------
// M2t[l][c][h*256+d] = sum_o linW[l][c][h*256+o] * W[l][h*256+o][d]   (bf16)
__global__ void k_prep_M2(const float* __restrict__ W, const float* __restrict__ linW,
                          unsigned short* __restrict__ M2t) {
    __shared__ float lsm[DD];
    int c = blockIdx.x, h = blockIdx.y, l = blockIdx.z, d = threadIdx.x;
    lsm[d] = linW[((size_t)l*DD + c)*HD + h*DD + d];
    __syncthreads();
    float acc = 0.f;
    for (int o = 0; o < DD; ++o)
        acc = fmaf(lsm[o], W[((size_t)l*HD + h*DD + o)*DD + d], acc);
    M2t[((size_t)l*DD + c)*HD + h*DD + d] = f2bf(acc);
}

// wsatt[l][h][k] = sum_o att_src[l][h][o]*W[l][h*256+o][k]; wdatt likewise
__global__ void k_prep_att(const float* __restrict__ W, const float* __restrict__ asrc, const float* __restrict__ adst,
                           float* __restrict__ wsatt, float* __restrict__ wdatt) {
    int h = blockIdx.x, l = blockIdx.y, k = threadIdx.x;
    float accs = 0.f, accd = 0.f;
    for (int d = 0; d < DD; ++d) {
        float w = W[l*HD*DD + (h*DD + d)*DD + k];
        accs += asrc[(l*HH + h)*DD + d] * w;
        accd += adst[(l*HH + h)*DD + d] * w;
    }
    wsatt[(l*HH + h)*DD + k] = accs;
    wdatt[(l*HH + h)*DD + k] = accd;
}

// bias2[l][c] = lin_b[l][c] + sum_u gat_bias[l][u]*linW[l][c][u]
__global__ void k_prep_bias(const float* __restrict__ gbias, const float* __restrict__ linW,
                            const float* __restrict__ linb, float* __restrict__ bias2) {
    int l = blockIdx.x, c = threadIdx.x;
    float acc = linb[l*DD + c];
    const float4* g4 = reinterpret_cast<const float4*>(gbias + l*HD);
    const float4* w4 = reinterpret_cast<const float4*>(linW + (size_t)l*DD*HD + (size_t)c*HD);
    for (int o = 0; o < HD/4; ++o) {
        float4 g = g4[o]; float4 w = w4[o];
        acc += g.x*w.x + g.y*w.y + g.z*w.z + g.w*w.w;
    }
    bias2[l*DD + c] = acc;
}

// ---------- f32 -> bf16 row conversion ----------
__global__ void k_tobf(const float* __restrict__ X, uint2* __restrict__ xb2) {
    int idx = blockIdx.x * 256 + threadIdx.x;      // over NPB*64
    float4 v = *(const float4*)(X + (size_t)idx * 4);
    uint2 o; o.x = pack2(v.x, v.y); o.y = pack2(v.z, v.w);
    xb2[idx] = o;
}

// ---------- attention scores a_s, a_d ----------
__global__ void k_attn_scores(const float* __restrict__ X, const float* __restrict__ ws_l, const float* __restrict__ wd_l,
                              float* __restrict__ a_s, float* __restrict__ a_d) {
    int tid = threadIdx.x;
    int g = blockIdx.x * 16 + (tid >> 4);
    int o = tid & 15;
    int h = o & 7;
    const float* wt = ((o < 8) ? ws_l : wd_l) + h*DD;
    const float4* x4 = reinterpret_cast<const float4*>(X + (size_t)g*DD);
    const float4* w4 = reinterpret_cast<const float4*>(wt);
    float acc = 0.f;
    #pragma unroll 8
    for (int k = 0; k < 64; ++k) {
        float4 x = x4[k], w = w4[k];
        acc += x.x*w.x + x.y*w.y + x.z*w.z + x.w*w.w;
    }
    if (o < 8) a_s[g*8 + h] = acc; else a_d[g*8 + h] = acc;
}

// ---------- aggregation of INPUT x per head: y[n,h,:] = sum alpha x[src] ----------
__global__ __launch_bounds__(256) void k_agg_y(const int* __restrict__ rowptr, const int* __restrict__ col,
                                               const float* __restrict__ a_s, const float* __restrict__ a_d,
                                               const uint2* __restrict__ xb2, uint2* __restrict__ y2,
                                               int node0) {
    int wave = threadIdx.x >> 6, lane = threadIdx.x & 63;
    int blk = blockIdx.x;
    // XCD swizzle: each XCD pair handles one graph -> x slice (2 MB bf16) is L2-resident
    int xcd = blk & 7, q = blk >> 3;
    int gl = xcd >> 1;
    int sub = ((xcd & 1) << 9) | q;
    int g = node0 + gl * NN + sub * 4 + wave;
    int b = g >> 12, n = g & (NN - 1);
    int rp = rowptr[b*(NN+1) + n], re = rowptr[b*(NN+1) + n + 1];
    const int* cl = col + (size_t)b * ENL;
    int gb = b * NN;
    int hl = lane & 7, slot = lane >> 3;
    float adh = a_d[(size_t)g * 8 + hl];
    float acc[8][4] = {};
    float sacc = 0.f;
    for (int e0 = rp; e0 < re; e0 += 8) {
        int e = e0 + slot;
        bool valid = e < re;
        int srcl = valid ? cl[e] : 0;
        float w = 0.f;
        if (valid) {
            float xs = a_s[(size_t)(gb + srcl) * 8 + hl] + adh;
            xs = (xs > 0.f) ? xs : 0.2f * xs;
            w = __expf(xs);           // no max-subtraction: scores bounded ~|25|, safe in f32
        }
        sacc += w;
        int cnt = re - e0; if (cnt > 8) cnt = 8;
        for (int i = 0; i < cnt; ++i) {
            int s = cl[e0 + i];
            uint2 u = xb2[(size_t)(gb + s) * 64 + lane];
            float x0 = bf_lo(u.x), x1 = bf_hi(u.x), x2 = bf_lo(u.y), x3 = bf_hi(u.y);
            #pragma unroll
            for (int h = 0; h < 8; ++h) {
                float wh = __shfl(w, i * 8 + h);
                acc[h][0] = fmaf(wh, x0, acc[h][0]);
                acc[h][1] = fmaf(wh, x1, acc[h][1]);
                acc[h][2] = fmaf(wh, x2, acc[h][2]);
                acc[h][3] = fmaf(wh, x3, acc[h][3]);
            }
        }
    }
    sacc += __shfl_xor(sacc, 8);
    sacc += __shfl_xor(sacc, 16);
    sacc += __shfl_xor(sacc, 32);
    float rinv = 1.f / (sacc + 1e-16f);
    uint2* yr = y2 + (size_t)(g - node0) * 512 + lane;
    #pragma unroll
    for (int h = 0; h < 8; ++h) {
        float rh = __shfl(rinv, h);
        uint2 o;
        o.x = pack2(acc[h][0] * rh, acc[h][1] * rh);
        o.y = pack2(acc[h][2] * rh, acc[h][3] * rh);
        yr[h * 64] = o;
    }
}

// ---------- out_tmp = y @ M2t^T  (MFMA bf16), tile 32x256, BK=64 ----------
__global__ __launch_bounds__(256) void k_gemm_out(const unsigned short* __restrict__ Yb,
                                                  const unsigned short* __restrict__ Bt,
                                                  float* __restrict__ tmp, int node0) {
    __shared__ float4 sbuf[2304];          // A: 32*128B=4KB, B: 256*128B=32KB
    char* lds = (char*)sbuf;
    int tid = threadIdx.x;
    int wv = tid >> 6, lane = tid & 63;
    int m0 = blockIdx.x * 32;
    f32x4 acc[2][4];
    #pragma unroll
    for (int mf = 0; mf < 2; ++mf)
        #pragma unroll
        for (int nf = 0; nf < 4; ++nf)
            acc[mf][nf] = (f32x4){0.f, 0.f, 0.f, 0.f};
    int ra = tid >> 3, ca = tid & 7;
    for (int kt = 0; kt < HD; kt += 64) {
        uint4 va = *(const uint4*)(Yb + (size_t)(m0 + ra) * HD + kt + ca * 8);
        uint4 vb[8];
        #pragma unroll
        for (int i = 0; i < 8; ++i) {
            int lam = i * 256 + tid;
            vb[i] = *(const uint4*)(Bt + (size_t)(lam >> 3) * HD + kt + (lam & 7) * 8);
        }
        __syncthreads();   // prev iteration's reads done
        *(uint4*)(lds + ra * 128 + ((ca * 16) ^ ((ra & 7) << 4))) = va;
        #pragma unroll
        for (int i = 0; i < 8; ++i) {
            int lam = i * 256 + tid;
            int r = lam >> 3, cb = (lam & 7) * 16;
            *(uint4*)(lds + 4096 + r * 128 + (cb ^ ((r & 7) << 4))) = vb[i];
        }
        __syncthreads();
        #pragma unroll
        for (int ks = 0; ks < 2; ++ks) {
            int kb = ks * 64 + ((lane >> 4) << 4);
            bf16x8 af[2], bfr[4];
            #pragma unroll
            for (int mf = 0; mf < 2; ++mf) {
                int r = mf * 16 + (lane & 15);
                af[mf] = *(bf16x8*)(lds + r * 128 + (kb ^ ((r & 7) << 4)));
            }
            #pragma unroll
            for (int nf = 0; nf < 4; ++nf) {
                int nr = wv * 64 + nf * 16 + (lane & 15);
                bfr[nf] = *(bf16x8*)(lds + 4096 + nr * 128 + (kb ^ ((nr & 7) << 4)));
            }
            #pragma unroll
            for (int mf = 0; mf < 2; ++mf)
                #pragma unroll
                for (int nf = 0; nf < 4; ++nf)
                    acc[mf][nf] = __builtin_amdgcn_mfma_f32_16x16x32_bf16(af[mf], bfr[nf], acc[mf][nf], 0, 0, 0);
        }
    }
    #pragma unroll
    for (int mf = 0; mf < 2; ++mf) {
        #pragma unroll
        for (int nf = 0; nf < 4; ++nf) {
            int colc = wv * 64 + nf * 16 + (lane & 15);
            #pragma unroll
            for (int rg = 0; rg < 4; ++rg) {
                int row = m0 + mf * 16 + ((lane >> 4) << 2) + rg;
                tmp[(size_t)(node0 + row) * DD + colc] = acc[mf][nf][rg];
            }
        }
    }
}

// ---------- +bias, LayerNorm, +res, relu; also emit bf16 x for next layer ----------
__global__ __launch_bounds__(256) void k_ln(const float* __restrict__ tmp, const float* __restrict__ bias2,
                                            const float* __restrict__ gamma, const float* __restrict__ beta,
                                            const float* __restrict__ res, float* __restrict__ out,
                                            uint2* __restrict__ xb2) {
    int wave = threadIdx.x >> 6, lane = threadIdx.x & 63;
    int g = blockIdx.x * 4 + wave;
    int c = lane * 4;
    float4 t = *(const float4*)(tmp + (size_t)g * DD + c);
    float4 b2 = *(const float4*)(bias2 + c);
    float g0 = t.x + b2.x, g1 = t.y + b2.y, g2 = t.z + b2.z, g3 = t.w + b2.w;
    float sum = g0 + g1 + g2 + g3;
    #pragma unroll
    for (int m = 1; m < 64; m <<= 1) sum += __shfl_xor(sum, m);
    float mu = sum * (1.f / 256.f);
    float d0 = g0 - mu, d1 = g1 - mu, d2 = g2 - mu, d3 = g3 - mu;
    float vs = d0*d0 + d1*d1 + d2*d2 + d3*d3;
    #pragma unroll
    for (int m = 1; m < 64; m <<= 1) vs += __shfl_xor(vs, m);
    float rstd = rsqrtf(vs * (1.f / 256.f) + 1e-5f);
    float4 gm = *(const float4*)(gamma + c);
    float4 bt = *(const float4*)(beta + c);
    float4 rs = *(const float4*)(res + (size_t)g * DD + c);
    float o0 = fmaxf(d0 * rstd * gm.x + bt.x + rs.x, 0.f);
    float o1 = fmaxf(d1 * rstd * gm.y + bt.y + rs.y, 0.f);
    float o2 = fmaxf(d2 * rstd * gm.z + bt.z + rs.z, 0.f);
    float o3 = fmaxf(d3 * rstd * gm.w + bt.w + rs.w, 0.f);
    *(float4*)(out + (size_t)g * DD + c) = make_float4(o0, o1, o2, o3);
    uint2 ob; ob.x = pack2(o0, o1); ob.y = pack2(o2, o3);
    xb2[(size_t)g * 64 + lane] = ob;
}

extern "C" void kernel_launch(void* const* d_in, const int* in_sizes, int n_in,
                              void* d_out, int out_size, void* d_ws, size_t ws_size,
                              hipStream_t stream) {
    const float* emb   = (const float*)d_in[0];
    const int*   edges = (const int*)d_in[1];
    const float* W     = (const float*)d_in[2];
    const float* asrc  = (const float*)d_in[3];
    const float* adst  = (const float*)d_in[4];
    const float* gbias = (const float*)d_in[5];
    const float* linW  = (const float*)d_in[6];
    const float* linb  = (const float*)d_in[7];
    const float* gam   = (const float*)d_in[8];
    const float* bet   = (const float*)d_in[9];
    float* out = (float*)d_out;

    // workspace layout (bytes), total ~126.4 MB
    char* ws = (char*)d_ws;
    uint2*          y2    = (uint2*)(ws + 0);               // 67108864  (CHUNK x 2048 bf16)
    float*          tmp   = (float*)(ws + 67108864);        // 33554432  (NPB x 256 f32)
    uint2*          xb2   = (uint2*)(ws + 100663296);       // 16777216  (NPB x 256 bf16)
    unsigned short* M2t   = (unsigned short*)(ws + 117440512); // 2097152 ([2][256][2048] bf16)
    float*          wsatt = (float*)(ws + 119537664);       // 16384
    float*          wdatt = (float*)(ws + 119554048);       // 16384
    float*          bias2 = (float*)(ws + 119570432);       // 2048
    float*          a_s   = (float*)(ws + 119572480);       // 1048576
    float*          a_d   = (float*)(ws + 120621056);       // 1048576
    int*            deg   = (int*)(ws + 121669632);         // 131072
    int*            cursor= (int*)(ws + 121800704);         // 131072
    int*            rowptr= (int*)(ws + 121931776);         // 131104
    int*            colx  = (int*)(ws + 122062880);         // 4325376

    hipMemsetAsync(deg, 0, BB*NN*sizeof(int), stream);
    k_count<<<dim3(BB*EE/256), 256, 0, stream>>>(edges, deg);
    k_scan<<<dim3(BB), 1024, 0, stream>>>(deg, rowptr, cursor);
    k_scatter<<<dim3((ENL+255)/256, BB), 256, 0, stream>>>(edges, cursor, colx);
    k_prep_M2<<<dim3(256, 8, 2), 256, 0, stream>>>(W, linW, M2t);
    k_prep_att<<<dim3(8, 2), 256, 0, stream>>>(W, asrc, adst, wsatt, wdatt);
    k_prep_bias<<<dim3(2), 256, 0, stream>>>(gbias, linW, linb, bias2);
    k_tobf<<<dim3(NPB*64/256), 256, 0, stream>>>(emb, xb2);

    for (int l = 0; l < 2; ++l) {
        const float* X = (l == 0) ? emb : out;
        k_attn_scores<<<dim3(NPB/16), 256, 0, stream>>>(X, wsatt + l*HH*DD, wdatt + l*HH*DD, a_s, a_d);
        for (int c = 0; c < 2; ++c) {
            int node0 = c * CHUNK;
            k_agg_y<<<dim3(CHUNK/4), 256, 0, stream>>>(rowptr, colx, a_s, a_d, xb2, y2, node0);
            k_gemm_out<<<dim3(CHUNK/32), 256, 0, stream>>>((const unsigned short*)y2,
                                                           M2t + (size_t)l*DD*HD, tmp, node0);
        }
        k_ln<<<dim3(NPB/4), 256, 0, stream>>>(tmp, bias2 + l*DD, gam, bet, X, out, xb2);
    }
}

// Round 3
// 884.290 us; speedup vs baseline: 2.9030x; 1.6236x over previous
//
#include <hip/hip_runtime.h>
#include <hip/hip_bf16.h>

#define BB 8
#define NN 4096
#define EE 131072          // edges per graph
#define ENL (EE + NN)      // + self loops
#define DD 256
#define HH 8
#define HD 2048
#define NPB (BB * NN)      // 32768 nodes total
#define CHUNK 16384        // nodes per y-chunk (4 graphs)

typedef __attribute__((ext_vector_type(8))) short bf16x8;
typedef __attribute__((ext_vector_type(4))) float f32x4;

static __device__ __forceinline__ float bf_lo(unsigned int u) { return __uint_as_float(u << 16); }
static __device__ __forceinline__ float bf_hi(unsigned int u) { return __uint_as_float(u & 0xFFFF0000u); }
static __device__ __forceinline__ unsigned short f2bf(float f) {
    __hip_bfloat16 h = __float2bfloat16(f);
    return *reinterpret_cast<unsigned short*>(&h);
}
static __device__ __forceinline__ unsigned int pack2(float a, float b) {
    return ((unsigned)f2bf(b) << 16) | f2bf(a);
}
static __device__ __forceinline__ void load_lds16(const void* g, void* l) {
    __builtin_amdgcn_global_load_lds(
        (const __attribute__((address_space(1))) unsigned int*)(g),
        (__attribute__((address_space(3))) unsigned int*)(l), 16, 0, 0);
}

// ---------- CSR build ----------
__global__ void k_count(const int* __restrict__ edges, int* __restrict__ deg) {
    int idx = blockIdx.x * 256 + threadIdx.x;
    int b = idx >> 17;
    int e = idx & (EE - 1);
    int dst = edges[b * 2 * EE + EE + e];
    atomicAdd(&deg[b * NN + dst], 1);
}

__global__ void k_scan(const int* __restrict__ deg, int* __restrict__ rowptr, int* __restrict__ cursor) {
    __shared__ int buf[1024];
    int b = blockIdx.x, t = threadIdx.x;
    int base = b * NN;
    int v0 = deg[base + t*4 + 0] + 1;
    int v1 = v0 + deg[base + t*4 + 1] + 1;
    int v2 = v1 + deg[base + t*4 + 2] + 1;
    int v3 = v2 + deg[base + t*4 + 3] + 1;
    buf[t] = v3; __syncthreads();
    for (int off = 1; off < 1024; off <<= 1) {
        int x = (t >= off) ? buf[t - off] : 0;
        __syncthreads();
        buf[t] += x;
        __syncthreads();
    }
    int excl = buf[t] - v3;
    int rp = b * (NN + 1);
    if (t == 0) rowptr[rp] = 0;
    rowptr[rp + t*4 + 1] = excl + v0;
    rowptr[rp + t*4 + 2] = excl + v1;
    rowptr[rp + t*4 + 3] = excl + v2;
    rowptr[rp + t*4 + 4] = excl + v3;
    cursor[base + t*4 + 0] = excl;
    cursor[base + t*4 + 1] = excl + v0;
    cursor[base + t*4 + 2] = excl + v1;
    cursor[base + t*4 + 3] = excl + v2;
}

__global__ void k_scatter(const int* __restrict__ edges, int* __restrict__ cursor, int* __restrict__ col) {
    int b = blockIdx.y;
    int idx = blockIdx.x * 256 + threadIdx.x;
    if (idx >= ENL) return;
    int src, dst;
    if (idx < EE) { src = edges[b*2*EE + idx]; dst = edges[b*2*EE + EE + idx]; }
    else { src = dst = idx - EE; }
    int pos = atomicAdd(&cursor[b*NN + dst], 1);
    col[b*ENL + pos] = src;
}

// ---------- weight precompute ----------
// M2t[l][c][h*256+d] = sum_o linW[l][c][h*256+o] * W[l][h*256+o][d]   (bf16)
__global__ void k_prep_M2(const float* __restrict__ W, const float* __restrict__ linW,
                          unsigned short* __restrict__ M2t) {
    __shared__ float lsm[DD];
    int c = blockIdx.x, h = blockIdx.y, l = blockIdx.z, d = threadIdx.x;
    lsm[d] = linW[((size_t)l*DD + c)*HD + h*DD + d];
    __syncthreads();
    float acc = 0.f;
    for (int o = 0; o < DD; ++o)
        acc = fmaf(lsm[o], W[((size_t)l*HD + h*DD + o)*DD + d], acc);
    M2t[((size_t)l*DD + c)*HD + h*DD + d] = f2bf(acc);
}

__global__ void k_prep_att(const float* __restrict__ W, const float* __restrict__ asrc, const float* __restrict__ adst,
                           float* __restrict__ wsatt, float* __restrict__ wdatt) {
    int h = blockIdx.x, l = blockIdx.y, k = threadIdx.x;
    float accs = 0.f, accd = 0.f;
    for (int d = 0; d < DD; ++d) {
        float w = W[l*HD*DD + (h*DD + d)*DD + k];
        accs += asrc[(l*HH + h)*DD + d] * w;
        accd += adst[(l*HH + h)*DD + d] * w;
    }
    wsatt[(l*HH + h)*DD + k] = accs;
    wdatt[(l*HH + h)*DD + k] = accd;
}

__global__ void k_prep_bias(const float* __restrict__ gbias, const float* __restrict__ linW,
                            const float* __restrict__ linb, float* __restrict__ bias2) {
    int l = blockIdx.x, c = threadIdx.x;
    float acc = linb[l*DD + c];
    const float4* g4 = reinterpret_cast<const float4*>(gbias + l*HD);
    const float4* w4 = reinterpret_cast<const float4*>(linW + (size_t)l*DD*HD + (size_t)c*HD);
    for (int o = 0; o < HD/4; ++o) {
        float4 g = g4[o]; float4 w = w4[o];
        acc += g.x*w.x + g.y*w.y + g.z*w.z + g.w*w.w;
    }
    bias2[l*DD + c] = acc;
}

// ---------- f32 -> bf16 row conversion ----------
__global__ void k_tobf(const float* __restrict__ X, uint2* __restrict__ xb2) {
    int idx = blockIdx.x * 256 + threadIdx.x;
    float4 v = *(const float4*)(X + (size_t)idx * 4);
    uint2 o; o.x = pack2(v.x, v.y); o.y = pack2(v.z, v.w);
    xb2[idx] = o;
}

// ---------- attention scores a_s, a_d ----------
__global__ void k_attn_scores(const float* __restrict__ X, const float* __restrict__ ws_l, const float* __restrict__ wd_l,
                              float* __restrict__ a_s, float* __restrict__ a_d) {
    int tid = threadIdx.x;
    int g = blockIdx.x * 16 + (tid >> 4);
    int o = tid & 15;
    int h = o & 7;
    const float* wt = ((o < 8) ? ws_l : wd_l) + h*DD;
    const float4* x4 = reinterpret_cast<const float4*>(X + (size_t)g*DD);
    const float4* w4 = reinterpret_cast<const float4*>(wt);
    float acc = 0.f;
    #pragma unroll 8
    for (int k = 0; k < 64; ++k) {
        float4 x = x4[k], w = w4[k];
        acc += x.x*w.x + x.y*w.y + x.z*w.z + x.w*w.w;
    }
    if (o < 8) a_s[g*8 + h] = acc; else a_d[g*8 + h] = acc;
}

// ---------- aggregation of INPUT x per head: y[n,h,:] = sum alpha x[src] ----------
__global__ __launch_bounds__(256) void k_agg_y(const int* __restrict__ rowptr, const int* __restrict__ col,
                                               const float* __restrict__ a_s, const float* __restrict__ a_d,
                                               const uint2* __restrict__ xb2, uint2* __restrict__ y2,
                                               int node0) {
    int wave = threadIdx.x >> 6, lane = threadIdx.x & 63;
    int blk = blockIdx.x;
    int xcd = blk & 7, q = blk >> 3;
    int gl = xcd >> 1;
    int sub = ((xcd & 1) << 9) | q;
    int g = node0 + gl * NN + sub * 4 + wave;
    int b = g >> 12, n = g & (NN - 1);
    int rp = rowptr[b*(NN+1) + n], re = rowptr[b*(NN+1) + n + 1];
    const int* cl = col + (size_t)b * ENL;
    int gb = b * NN;
    int hl = lane & 7, slot = lane >> 3;
    float adh = a_d[(size_t)g * 8 + hl];
    float acc[8][4] = {};
    float sacc = 0.f;
    for (int e0 = rp; e0 < re; e0 += 8) {
        int e = e0 + slot;
        bool valid = e < re;
        int srcl = valid ? cl[e] : 0;
        float w = 0.f;
        if (valid) {
            float xs = a_s[(size_t)(gb + srcl) * 8 + hl] + adh;
            xs = (xs > 0.f) ? xs : 0.2f * xs;
            w = __expf(xs);           // no max-subtraction: scores bounded, safe in f32
        }
        sacc += w;
        if (e0 + 8 <= re) {
            #pragma unroll
            for (int i = 0; i < 8; ++i) {
                int s = __shfl(srcl, i * 8);          // index already in regs: no global reload
                uint2 u = xb2[(size_t)(gb + s) * 64 + lane];
                float x0 = bf_lo(u.x), x1 = bf_hi(u.x), x2 = bf_lo(u.y), x3 = bf_hi(u.y);
                #pragma unroll
                for (int h = 0; h < 8; ++h) {
                    float wh = __shfl(w, i * 8 + h);
                    acc[h][0] = fmaf(wh, x0, acc[h][0]);
                    acc[h][1] = fmaf(wh, x1, acc[h][1]);
                    acc[h][2] = fmaf(wh, x2, acc[h][2]);
                    acc[h][3] = fmaf(wh, x3, acc[h][3]);
                }
            }
        } else {
            int cnt = re - e0;
            for (int i = 0; i < cnt; ++i) {
                int s = __shfl(srcl, i * 8);
                uint2 u = xb2[(size_t)(gb + s) * 64 + lane];
                float x0 = bf_lo(u.x), x1 = bf_hi(u.x), x2 = bf_lo(u.y), x3 = bf_hi(u.y);
                #pragma unroll
                for (int h = 0; h < 8; ++h) {
                    float wh = __shfl(w, i * 8 + h);
                    acc[h][0] = fmaf(wh, x0, acc[h][0]);
                    acc[h][1] = fmaf(wh, x1, acc[h][1]);
                    acc[h][2] = fmaf(wh, x2, acc[h][2]);
                    acc[h][3] = fmaf(wh, x3, acc[h][3]);
                }
            }
        }
    }
    sacc += __shfl_xor(sacc, 8);
    sacc += __shfl_xor(sacc, 16);
    sacc += __shfl_xor(sacc, 32);
    float rinv = 1.f / (sacc + 1e-16f);
    uint2* yr = y2 + (size_t)(g - node0) * 512 + lane;
    #pragma unroll
    for (int h = 0; h < 8; ++h) {
        float rh = __shfl(rinv, h);
        uint2 o;
        o.x = pack2(acc[h][0] * rh, acc[h][1] * rh);
        o.y = pack2(acc[h][2] * rh, acc[h][3] * rh);
        yr[h * 64] = o;
    }
}

// ---------- fused: tmp = y @ M2t^T (MFMA) -> +bias -> LN -> +res -> relu -> out + xb2 ----------
// tile 32(M) x 256(N), BK=128, 256 threads (4 waves, wave_n split)
__global__ __launch_bounds__(256) void k_gemm_ln(const unsigned short* __restrict__ Yb,
                                                 const unsigned short* __restrict__ Bt,
                                                 const float* __restrict__ bias2,
                                                 const float* __restrict__ gamma,
                                                 const float* __restrict__ beta,
                                                 const float* __restrict__ res,
                                                 float* __restrict__ out,
                                                 unsigned int* __restrict__ xb,
                                                 int node0) {
    __shared__ char lds[73728 + 2048];   // A 8KB @0, B 64KB @8192, LN scratch @73728
    int tid = threadIdx.x;
    int wv = tid >> 6, lane = tid & 63;
    int m0 = blockIdx.x * 32;
    int c = lane & 15, q = lane >> 4;
    f32x4 acc[2][4];
    #pragma unroll
    for (int mf = 0; mf < 2; ++mf)
        #pragma unroll
        for (int nf = 0; nf < 4; ++nf) acc[mf][nf] = (f32x4){0.f, 0.f, 0.f, 0.f};

    for (int kt = 0; kt < HD; kt += 128) {
        // stage A-tile (32 rows x 128 k): 8 wave-iters, this wave does 2.
        // linear LDS dest; global source pre-swizzled (chunk j' = j ^ (row&15))
        #pragma unroll
        for (int it = 0; it < 2; ++it) {
            int iter = wv * 2 + it;
            int ci = iter * 64 + lane;
            int row = ci >> 4, j = ci & 15;
            int jp = j ^ (row & 15);
            load_lds16(Yb + (size_t)(m0 + row) * HD + kt + jp * 8, lds + iter * 1024);
        }
        // stage B-tile (256 rows x 128 k): 64 wave-iters, this wave does 16
        #pragma unroll
        for (int it = 0; it < 16; ++it) {
            int iter = wv * 16 + it;
            int ci = iter * 64 + lane;
            int row = ci >> 4, j = ci & 15;
            int jp = j ^ (row & 15);
            load_lds16(Bt + (size_t)row * HD + kt + jp * 8, lds + 8192 + iter * 1024);
        }
        __syncthreads();   // vmcnt drain + barrier: LDS tiles ready
        #pragma unroll
        for (int ks = 0; ks < 4; ++ks) {
            int kb = ks * 64 + (q << 4);
            bf16x8 af[2], bfr[4];
            #pragma unroll
            for (int mf = 0; mf < 2; ++mf) {
                int r = mf * 16 + c;
                af[mf] = *(const bf16x8*)(lds + r * 256 + (kb ^ ((r & 15) << 4)));
            }
            #pragma unroll
            for (int nf = 0; nf < 4; ++nf) {
                int nr = wv * 64 + nf * 16 + c;
                bfr[nf] = *(const bf16x8*)(lds + 8192 + nr * 256 + (kb ^ ((nr & 15) << 4)));
            }
            #pragma unroll
            for (int mf = 0; mf < 2; ++mf)
                #pragma unroll
                for (int nf = 0; nf < 4; ++nf)
                    acc[mf][nf] = __builtin_amdgcn_mfma_f32_16x16x32_bf16(af[mf], bfr[nf], acc[mf][nf], 0, 0, 0);
        }
        __syncthreads();   // all reads done before next stage overwrites
    }

    // ---- epilogue: +bias, LayerNorm (cross-wave via LDS), +res, relu, emit f32 + bf16 ----
    float2* lnbuf = (float2*)(lds + 73728);         // [32][4]
    float2* musd  = (float2*)(lds + 73728 + 1024);  // [32]
    float b2[4], gmv[4], btv[4];
    #pragma unroll
    for (int nf = 0; nf < 4; ++nf) {
        int colx = wv * 64 + nf * 16 + c;
        b2[nf] = bias2[colx]; gmv[nf] = gamma[colx]; btv[nf] = beta[colx];
    }
    #pragma unroll
    for (int mf = 0; mf < 2; ++mf)
        #pragma unroll
        for (int nf = 0; nf < 4; ++nf)
            #pragma unroll
            for (int rg = 0; rg < 4; ++rg)
                acc[mf][nf][rg] += b2[nf];
    #pragma unroll
    for (int mf = 0; mf < 2; ++mf) {
        #pragma unroll
        for (int rg = 0; rg < 4; ++rg) {
            float s = 0.f, ss = 0.f;
            #pragma unroll
            for (int nf = 0; nf < 4; ++nf) { float v = acc[mf][nf][rg]; s += v; ss += v * v; }
            #pragma unroll
            for (int msk = 1; msk < 16; msk <<= 1) { s += __shfl_xor(s, msk); ss += __shfl_xor(ss, msk); }
            if (c == 0) lnbuf[(mf * 16 + q * 4 + rg) * 4 + wv] = make_float2(s, ss);
        }
    }
    __syncthreads();
    if (tid < 32) {
        float s = 0.f, ss = 0.f;
        #pragma unroll
        for (int w = 0; w < 4; ++w) { float2 p = lnbuf[tid * 4 + w]; s += p.x; ss += p.y; }
        float mu = s * (1.f / 256.f);
        float var = ss * (1.f / 256.f) - mu * mu;
        musd[tid] = make_float2(mu, rsqrtf(var + 1e-5f));
    }
    __syncthreads();
    #pragma unroll
    for (int mf = 0; mf < 2; ++mf) {
        #pragma unroll
        for (int rg = 0; rg < 4; ++rg) {
            int row = mf * 16 + q * 4 + rg;
            float2 ms = musd[row];
            size_t grow = (size_t)(node0 + m0 + row);
            #pragma unroll
            for (int nf = 0; nf < 4; ++nf) {
                int colx = wv * 64 + nf * 16 + c;
                float o = (acc[mf][nf][rg] - ms.x) * ms.y * gmv[nf] + btv[nf] + res[grow * DD + colx];
                o = fmaxf(o, 0.f);
                out[grow * DD + colx] = o;
                float nb = __shfl_xor(o, 1);
                if (!(c & 1)) xb[grow * 128 + (colx >> 1)] = pack2(o, nb);
            }
        }
    }
}

extern "C" void kernel_launch(void* const* d_in, const int* in_sizes, int n_in,
                              void* d_out, int out_size, void* d_ws, size_t ws_size,
                              hipStream_t stream) {
    const float* emb   = (const float*)d_in[0];
    const int*   edges = (const int*)d_in[1];
    const float* W     = (const float*)d_in[2];
    const float* asrc  = (const float*)d_in[3];
    const float* adst  = (const float*)d_in[4];
    const float* gbias = (const float*)d_in[5];
    const float* linW  = (const float*)d_in[6];
    const float* linb  = (const float*)d_in[7];
    const float* gam   = (const float*)d_in[8];
    const float* bet   = (const float*)d_in[9];
    float* out = (float*)d_out;

    // workspace layout (bytes), total ~88.6 MB
    char* ws = (char*)d_ws;
    uint2*          y2    = (uint2*)(ws + 0);                  // 67108864 (CHUNK x 2048 bf16)
    uint2*          xb2   = (uint2*)(ws + 67108864);           // 16777216 (NPB x 256 bf16)
    unsigned short* M2t   = (unsigned short*)(ws + 83886080);  // 2097152  ([2][256][2048] bf16)
    float*          wsatt = (float*)(ws + 85983232);           // 16384
    float*          wdatt = (float*)(ws + 85999616);           // 16384
    float*          bias2 = (float*)(ws + 86016000);           // 2048
    float*          a_s   = (float*)(ws + 86018048);           // 1048576
    float*          a_d   = (float*)(ws + 87066624);           // 1048576
    int*            deg   = (int*)(ws + 88115200);             // 131072
    int*            cursor= (int*)(ws + 88246272);             // 131072
    int*            rowptr= (int*)(ws + 88377344);             // 131104
    int*            colx  = (int*)(ws + 88508448);             // 4325376

    hipMemsetAsync(deg, 0, BB*NN*sizeof(int), stream);
    k_count<<<dim3(BB*EE/256), 256, 0, stream>>>(edges, deg);
    k_scan<<<dim3(BB), 1024, 0, stream>>>(deg, rowptr, cursor);
    k_scatter<<<dim3((ENL+255)/256, BB), 256, 0, stream>>>(edges, cursor, colx);
    k_prep_M2<<<dim3(256, 8, 2), 256, 0, stream>>>(W, linW, M2t);
    k_prep_att<<<dim3(8, 2), 256, 0, stream>>>(W, asrc, adst, wsatt, wdatt);
    k_prep_bias<<<dim3(2), 256, 0, stream>>>(gbias, linW, linb, bias2);
    k_tobf<<<dim3(NPB*64/256), 256, 0, stream>>>(emb, xb2);

    for (int l = 0; l < 2; ++l) {
        const float* X = (l == 0) ? emb : out;
        k_attn_scores<<<dim3(NPB/16), 256, 0, stream>>>(X, wsatt + l*HH*DD, wdatt + l*HH*DD, a_s, a_d);
        for (int cc = 0; cc < 2; ++cc) {
            int node0 = cc * CHUNK;
            k_agg_y<<<dim3(CHUNK/4), 256, 0, stream>>>(rowptr, colx, a_s, a_d, xb2, y2, node0);
            k_gemm_ln<<<dim3(CHUNK/32), 256, 0, stream>>>((const unsigned short*)y2,
                                                          M2t + (size_t)l*DD*HD, bias2 + l*DD,
                                                          gam, bet, X, out,
                                                          (unsigned int*)xb2, node0);
        }
    }
}

// Round 4
// 703.084 us; speedup vs baseline: 3.6512x; 1.2577x over previous
//
#include <hip/hip_runtime.h>
#include <hip/hip_bf16.h>

#define BB 8
#define NN 4096
#define EE 131072          // edges per graph
#define ENL (EE + NN)      // + self loops
#define DD 256
#define HH 8
#define HD 2048
#define NPB (BB * NN)      // 32768 nodes total
#define CHUNK 16384        // nodes per y-chunk (4 graphs)

typedef __attribute__((ext_vector_type(8))) short bf16x8;
typedef __attribute__((ext_vector_type(4))) float f32x4;

static __device__ __forceinline__ float bf_lo(unsigned int u) { return __uint_as_float(u << 16); }
static __device__ __forceinline__ float bf_hi(unsigned int u) { return __uint_as_float(u & 0xFFFF0000u); }
static __device__ __forceinline__ unsigned short f2bf(float f) {
    __hip_bfloat16 h = __float2bfloat16(f);
    return *reinterpret_cast<unsigned short*>(&h);
}
static __device__ __forceinline__ unsigned int pack2(float a, float b) {
    return ((unsigned)f2bf(b) << 16) | f2bf(a);
}
static __device__ __forceinline__ void load_lds16(const void* g, void* l) {
    __builtin_amdgcn_global_load_lds(
        (const __attribute__((address_space(1))) unsigned int*)(g),
        (__attribute__((address_space(3))) unsigned int*)(l), 16, 0, 0);
}
static __device__ __forceinline__ float rl_f(float v, int lane) {
    return __uint_as_float(__builtin_amdgcn_readlane(__float_as_uint(v), lane));
}

// ---------- CSR build ----------
__global__ void k_count(const int* __restrict__ edges, int* __restrict__ deg) {
    int idx = blockIdx.x * 256 + threadIdx.x;
    int b = idx >> 17;
    int e = idx & (EE - 1);
    int dst = edges[b * 2 * EE + EE + e];
    atomicAdd(&deg[b * NN + dst], 1);
}

__global__ void k_scan(const int* __restrict__ deg, int* __restrict__ rowptr, int* __restrict__ cursor) {
    __shared__ int buf[1024];
    int b = blockIdx.x, t = threadIdx.x;
    int base = b * NN;
    int v0 = deg[base + t*4 + 0] + 1;
    int v1 = v0 + deg[base + t*4 + 1] + 1;
    int v2 = v1 + deg[base + t*4 + 2] + 1;
    int v3 = v2 + deg[base + t*4 + 3] + 1;
    buf[t] = v3; __syncthreads();
    for (int off = 1; off < 1024; off <<= 1) {
        int x = (t >= off) ? buf[t - off] : 0;
        __syncthreads();
        buf[t] += x;
        __syncthreads();
    }
    int excl = buf[t] - v3;
    int rp = b * (NN + 1);
    if (t == 0) rowptr[rp] = 0;
    rowptr[rp + t*4 + 1] = excl + v0;
    rowptr[rp + t*4 + 2] = excl + v1;
    rowptr[rp + t*4 + 3] = excl + v2;
    rowptr[rp + t*4 + 4] = excl + v3;
    cursor[base + t*4 + 0] = excl;
    cursor[base + t*4 + 1] = excl + v0;
    cursor[base + t*4 + 2] = excl + v1;
    cursor[base + t*4 + 3] = excl + v2;
}

__global__ void k_scatter(const int* __restrict__ edges, int* __restrict__ cursor, int* __restrict__ col) {
    int b = blockIdx.y;
    int idx = blockIdx.x * 256 + threadIdx.x;
    if (idx >= ENL) return;
    int src, dst;
    if (idx < EE) { src = edges[b*2*EE + idx]; dst = edges[b*2*EE + EE + idx]; }
    else { src = dst = idx - EE; }
    int pos = atomicAdd(&cursor[b*NN + dst], 1);
    col[b*ENL + pos] = src;
}

// ---------- weight precompute ----------
__global__ void k_prep_M2(const float* __restrict__ W, const float* __restrict__ linW,
                          unsigned short* __restrict__ M2t) {
    __shared__ float lsm[DD];
    int c = blockIdx.x, h = blockIdx.y, l = blockIdx.z, d = threadIdx.x;
    lsm[d] = linW[((size_t)l*DD + c)*HD + h*DD + d];
    __syncthreads();
    float acc = 0.f;
    for (int o = 0; o < DD; ++o)
        acc = fmaf(lsm[o], W[((size_t)l*HD + h*DD + o)*DD + d], acc);
    M2t[((size_t)l*DD + c)*HD + h*DD + d] = f2bf(acc);
}

__global__ void k_prep_att(const float* __restrict__ W, const float* __restrict__ asrc, const float* __restrict__ adst,
                           float* __restrict__ wsatt, float* __restrict__ wdatt) {
    int h = blockIdx.x, l = blockIdx.y, k = threadIdx.x;
    float accs = 0.f, accd = 0.f;
    for (int d = 0; d < DD; ++d) {
        float w = W[l*HD*DD + (h*DD + d)*DD + k];
        accs += asrc[(l*HH + h)*DD + d] * w;
        accd += adst[(l*HH + h)*DD + d] * w;
    }
    wsatt[(l*HH + h)*DD + k] = accs;
    wdatt[(l*HH + h)*DD + k] = accd;
}

// pack folded attention weights into exact MFMA B-fragment layout:
// frag[l][t=ks*64+lane][j], col=lane&15 (0-7: src, 8-15: dst), k = ks*32 + (lane>>4)*8 + j
__global__ void k_prep_attfrag(const float* __restrict__ ws, const float* __restrict__ wd,
                               unsigned short* __restrict__ frag) {
    int l = blockIdx.x, t = threadIdx.x;           // 512 threads
    int ks = t >> 6, lane = t & 63, c = lane & 15, q = lane >> 4;
    #pragma unroll
    for (int j = 0; j < 8; ++j) {
        int k = ks * 32 + q * 8 + j;
        float v = (c < 8) ? ws[(l*HH + c)*DD + k] : wd[(l*HH + (c-8))*DD + k];
        frag[((size_t)l*512 + t)*8 + j] = f2bf(v);
    }
}

__global__ void k_prep_bias(const float* __restrict__ gbias, const float* __restrict__ linW,
                            const float* __restrict__ linb, float* __restrict__ bias2) {
    int l = blockIdx.x, c = threadIdx.x;
    float acc = linb[l*DD + c];
    const float4* g4 = reinterpret_cast<const float4*>(gbias + l*HD);
    const float4* w4 = reinterpret_cast<const float4*>(linW + (size_t)l*DD*HD + (size_t)c*HD);
    for (int o = 0; o < HD/4; ++o) {
        float4 g = g4[o]; float4 w = w4[o];
        acc += g.x*w.x + g.y*w.y + g.z*w.z + g.w*w.w;
    }
    bias2[l*DD + c] = acc;
}

// ---------- f32 -> bf16 row conversion ----------
__global__ void k_tobf(const float* __restrict__ X, uint2* __restrict__ xb2) {
    int idx = blockIdx.x * 256 + threadIdx.x;
    float4 v = *(const float4*)(X + (size_t)idx * 4);
    uint2 o; o.x = pack2(v.x, v.y); o.y = pack2(v.z, v.w);
    xb2[idx] = o;
}

// ---------- attention scores via MFMA: [N x 256] @ [256 x 16] ----------
__global__ __launch_bounds__(256) void k_attn_mfma(const unsigned short* __restrict__ xb,
                                                   const unsigned short* __restrict__ attfrag,
                                                   float* __restrict__ a_s, float* __restrict__ a_d) {
    int tid = threadIdx.x;
    int wv = tid >> 6, lane = tid & 63;
    int m0 = blockIdx.x * 64 + wv * 16;
    int c = lane & 15, q = lane >> 4;
    const unsigned short* arow = xb + (size_t)(m0 + c) * DD;
    f32x4 acc = (f32x4){0.f, 0.f, 0.f, 0.f};
    #pragma unroll
    for (int ks = 0; ks < 8; ++ks) {
        bf16x8 af = *(const bf16x8*)(arow + ks * 32 + q * 8);
        bf16x8 bf = *(const bf16x8*)(attfrag + (size_t)(ks * 64 + lane) * 8);
        acc = __builtin_amdgcn_mfma_f32_16x16x32_bf16(af, bf, acc, 0, 0, 0);
    }
    #pragma unroll
    for (int rg = 0; rg < 4; ++rg) {
        int row = m0 + q * 4 + rg;
        if (c < 8) a_s[row * 8 + c] = acc[rg];
        else       a_d[row * 8 + (c - 8)] = acc[rg];
    }
}

// ---------- aggregation of INPUT x per head: y[n,h,:] = sum alpha x[src] ----------
__global__ __launch_bounds__(256) void k_agg_y(const int* __restrict__ rowptr, const int* __restrict__ col,
                                               const float* __restrict__ a_s, const float* __restrict__ a_d,
                                               const uint2* __restrict__ xb2, uint2* __restrict__ y2,
                                               int node0) {
    int wave = threadIdx.x >> 6, lane = threadIdx.x & 63;
    int blk = blockIdx.x;
    int xcd = blk & 7, q = blk >> 3;
    int gl = xcd >> 1;
    int sub = ((xcd & 1) << 9) | q;
    int g = node0 + gl * NN + sub * 4 + wave;
    int b = g >> 12, n = g & (NN - 1);
    int rp = rowptr[b*(NN+1) + n], re = rowptr[b*(NN+1) + n + 1];
    const int* cl = col + (size_t)b * ENL;
    int gb = b * NN;
    int hl = lane & 7, slot = lane >> 3;
    float adh = a_d[(size_t)g * 8 + hl];
    float acc[8][4] = {};
    float sacc = 0.f;
    for (int e0 = rp; e0 < re; e0 += 8) {
        int e = e0 + slot;
        bool valid = e < re;
        int srcl = valid ? cl[e] : 0;
        float w = 0.f;
        if (valid) {
            float xs = a_s[(size_t)(gb + srcl) * 8 + hl] + adh;
            xs = (xs > 0.f) ? xs : 0.2f * xs;
            w = __expf(xs);           // no max-subtraction: scores bounded, safe in f32
        }
        sacc += w;
        if (e0 + 8 <= re) {
            #pragma unroll
            for (int i = 0; i < 8; ++i) {
                int s = __builtin_amdgcn_readlane(srcl, i * 8);   // SGPR: scalar gather base
                uint2 u = xb2[(size_t)(gb + s) * 64 + lane];
                float x0 = bf_lo(u.x), x1 = bf_hi(u.x), x2 = bf_lo(u.y), x3 = bf_hi(u.y);
                #pragma unroll
                for (int h = 0; h < 8; ++h) {
                    float wh = rl_f(w, i * 8 + h);                // SGPR multiplier
                    acc[h][0] = fmaf(wh, x0, acc[h][0]);
                    acc[h][1] = fmaf(wh, x1, acc[h][1]);
                    acc[h][2] = fmaf(wh, x2, acc[h][2]);
                    acc[h][3] = fmaf(wh, x3, acc[h][3]);
                }
            }
        } else {
            int cnt = re - e0;
            for (int i = 0; i < cnt; ++i) {
                int s = __builtin_amdgcn_readlane(srcl, i * 8);
                uint2 u = xb2[(size_t)(gb + s) * 64 + lane];
                float x0 = bf_lo(u.x), x1 = bf_hi(u.x), x2 = bf_lo(u.y), x3 = bf_hi(u.y);
                #pragma unroll
                for (int h = 0; h < 8; ++h) {
                    float wh = rl_f(w, i * 8 + h);
                    acc[h][0] = fmaf(wh, x0, acc[h][0]);
                    acc[h][1] = fmaf(wh, x1, acc[h][1]);
                    acc[h][2] = fmaf(wh, x2, acc[h][2]);
                    acc[h][3] = fmaf(wh, x3, acc[h][3]);
                }
            }
        }
    }
    sacc += __shfl_xor(sacc, 8);
    sacc += __shfl_xor(sacc, 16);
    sacc += __shfl_xor(sacc, 32);
    float rinv = 1.f / (sacc + 1e-16f);
    uint2* yr = y2 + (size_t)(g - node0) * 512 + lane;
    #pragma unroll
    for (int h = 0; h < 8; ++h) {
        float rh = rl_f(rinv, h);
        uint2 o;
        o.x = pack2(acc[h][0] * rh, acc[h][1] * rh);
        o.y = pack2(acc[h][2] * rh, acc[h][3] * rh);
        yr[h * 64] = o;
    }
}

// ---------- fused: y @ M2t^T (MFMA) -> +bias -> LN -> +res -> relu -> out + xb2 ----------
// tile 64(M) x 256(N), BK=128, 512 threads (8 waves, each 64M x 32N)
__global__ __launch_bounds__(512) void k_gemm_ln(const unsigned short* __restrict__ Yb,
                                                 const unsigned short* __restrict__ Bt,
                                                 const float* __restrict__ bias2,
                                                 const float* __restrict__ gamma,
                                                 const float* __restrict__ beta,
                                                 const float* __restrict__ res,
                                                 float* __restrict__ out,
                                                 unsigned int* __restrict__ xb,
                                                 int node0) {
    __shared__ char lds[81920];   // A 16KB @0, B 64KB @16384; epilogue scratch overlays A
    int tid = threadIdx.x;
    int wv = tid >> 6, lane = tid & 63;
    int m0 = blockIdx.x * 64;
    int c = lane & 15, q = lane >> 4;
    f32x4 acc[4][2];
    #pragma unroll
    for (int mf = 0; mf < 4; ++mf)
        #pragma unroll
        for (int nf = 0; nf < 2; ++nf) acc[mf][nf] = (f32x4){0.f, 0.f, 0.f, 0.f};

    for (int kt = 0; kt < HD; kt += 128) {
        // A-tile 64 x 128k = 1024 chunks of 16B; pre-swizzled source, linear LDS dest
        #pragma unroll
        for (int it = 0; it < 2; ++it) {
            int ci = it * 512 + wv * 64 + lane;
            int row = ci >> 4, j = ci & 15, jp = j ^ (row & 15);
            load_lds16(Yb + (size_t)(m0 + row) * HD + kt + jp * 8, lds + it * 8192 + wv * 1024);
        }
        // B-tile 256 x 128k = 4096 chunks
        #pragma unroll
        for (int it = 0; it < 8; ++it) {
            int ci = it * 512 + wv * 64 + lane;
            int row = ci >> 4, j = ci & 15, jp = j ^ (row & 15);
            load_lds16(Bt + (size_t)row * HD + kt + jp * 8, lds + 16384 + it * 8192 + wv * 1024);
        }
        __syncthreads();
        #pragma unroll
        for (int ks = 0; ks < 4; ++ks) {
            int kb = ks * 64 + (q << 4);
            bf16x8 af[4], bfr[2];
            #pragma unroll
            for (int mf = 0; mf < 4; ++mf) {
                int r = mf * 16 + c;
                af[mf] = *(const bf16x8*)(lds + r * 256 + (kb ^ ((r & 15) << 4)));
            }
            #pragma unroll
            for (int nf = 0; nf < 2; ++nf) {
                int nr = wv * 32 + nf * 16 + c;
                bfr[nf] = *(const bf16x8*)(lds + 16384 + nr * 256 + (kb ^ ((nr & 15) << 4)));
            }
            #pragma unroll
            for (int mf = 0; mf < 4; ++mf)
                #pragma unroll
                for (int nf = 0; nf < 2; ++nf)
                    acc[mf][nf] = __builtin_amdgcn_mfma_f32_16x16x32_bf16(af[mf], bfr[nf], acc[mf][nf], 0, 0, 0);
        }
        __syncthreads();
    }

    // ---- epilogue: +bias, LayerNorm (cross-wave via LDS), +res, relu, f32 + bf16 emit ----
    float2* lnbuf = (float2*)lds;             // [64][8] float2 = 4KB
    float2* musd  = (float2*)(lds + 4096);    // [64]
    float b2[2], gmv[2], btv[2];
    #pragma unroll
    for (int nf = 0; nf < 2; ++nf) {
        int colx = wv * 32 + nf * 16 + c;
        b2[nf] = bias2[colx]; gmv[nf] = gamma[colx]; btv[nf] = beta[colx];
    }
    #pragma unroll
    for (int mf = 0; mf < 4; ++mf)
        #pragma unroll
        for (int nf = 0; nf < 2; ++nf)
            #pragma unroll
            for (int rg = 0; rg < 4; ++rg)
                acc[mf][nf][rg] += b2[nf];
    #pragma unroll
    for (int mf = 0; mf < 4; ++mf) {
        #pragma unroll
        for (int rg = 0; rg < 4; ++rg) {
            float s = 0.f, ss = 0.f;
            #pragma unroll
            for (int nf = 0; nf < 2; ++nf) { float v = acc[mf][nf][rg]; s += v; ss += v * v; }
            #pragma unroll
            for (int msk = 1; msk < 16; msk <<= 1) { s += __shfl_xor(s, msk); ss += __shfl_xor(ss, msk); }
            if (c == 0) lnbuf[(mf * 16 + q * 4 + rg) * 8 + wv] = make_float2(s, ss);
        }
    }
    __syncthreads();
    if (tid < 64) {
        float s = 0.f, ss = 0.f;
        #pragma unroll
        for (int w = 0; w < 8; ++w) { float2 p = lnbuf[tid * 8 + w]; s += p.x; ss += p.y; }
        float mu = s * (1.f / 256.f);
        float var = ss * (1.f / 256.f) - mu * mu;
        musd[tid] = make_float2(mu, rsqrtf(var + 1e-5f));
    }
    __syncthreads();
    #pragma unroll
    for (int mf = 0; mf < 4; ++mf) {
        #pragma unroll
        for (int rg = 0; rg < 4; ++rg) {
            int row = mf * 16 + q * 4 + rg;
            float2 ms = musd[row];
            size_t grow = (size_t)(node0 + m0 + row);
            #pragma unroll
            for (int nf = 0; nf < 2; ++nf) {
                int colx = wv * 32 + nf * 16 + c;
                float o = (acc[mf][nf][rg] - ms.x) * ms.y * gmv[nf] + btv[nf] + res[grow * DD + colx];
                o = fmaxf(o, 0.f);
                out[grow * DD + colx] = o;
                float nb = __shfl_xor(o, 1);
                if (!(c & 1)) xb[grow * 128 + (colx >> 1)] = pack2(o, nb);
            }
        }
    }
}

extern "C" void kernel_launch(void* const* d_in, const int* in_sizes, int n_in,
                              void* d_out, int out_size, void* d_ws, size_t ws_size,
                              hipStream_t stream) {
    const float* emb   = (const float*)d_in[0];
    const int*   edges = (const int*)d_in[1];
    const float* W     = (const float*)d_in[2];
    const float* asrc  = (const float*)d_in[3];
    const float* adst  = (const float*)d_in[4];
    const float* gbias = (const float*)d_in[5];
    const float* linW  = (const float*)d_in[6];
    const float* linb  = (const float*)d_in[7];
    const float* gam   = (const float*)d_in[8];
    const float* bet   = (const float*)d_in[9];
    float* out = (float*)d_out;

    // workspace layout (bytes), total ~92.9 MB
    char* ws = (char*)d_ws;
    uint2*          y2      = (uint2*)(ws + 0);                  // 67108864 (CHUNK x 2048 bf16)
    uint2*          xb2     = (uint2*)(ws + 67108864);           // 16777216 (NPB x 256 bf16)
    unsigned short* M2t     = (unsigned short*)(ws + 83886080);  // 2097152
    float*          wsatt   = (float*)(ws + 85983232);           // 16384
    float*          wdatt   = (float*)(ws + 85999616);           // 16384
    float*          bias2   = (float*)(ws + 86016000);           // 2048
    float*          a_s     = (float*)(ws + 86018048);           // 1048576
    float*          a_d     = (float*)(ws + 87066624);           // 1048576
    int*            deg     = (int*)(ws + 88115200);             // 131072
    int*            cursor  = (int*)(ws + 88246272);             // 131072
    int*            rowptr  = (int*)(ws + 88377344);             // 131104
    int*            colx    = (int*)(ws + 88508448);             // 4325376
    unsigned short* attfrag = (unsigned short*)(ws + 92833824);  // 16384

    hipMemsetAsync(deg, 0, BB*NN*sizeof(int), stream);
    k_count<<<dim3(BB*EE/256), 256, 0, stream>>>(edges, deg);
    k_scan<<<dim3(BB), 1024, 0, stream>>>(deg, rowptr, cursor);
    k_scatter<<<dim3((ENL+255)/256, BB), 256, 0, stream>>>(edges, cursor, colx);
    k_prep_M2<<<dim3(256, 8, 2), 256, 0, stream>>>(W, linW, M2t);
    k_prep_att<<<dim3(8, 2), 256, 0, stream>>>(W, asrc, adst, wsatt, wdatt);
    k_prep_attfrag<<<dim3(2), 512, 0, stream>>>(wsatt, wdatt, attfrag);
    k_prep_bias<<<dim3(2), 256, 0, stream>>>(gbias, linW, linb, bias2);
    k_tobf<<<dim3(NPB*64/256), 256, 0, stream>>>(emb, xb2);

    for (int l = 0; l < 2; ++l) {
        const float* X = (l == 0) ? emb : out;
        k_attn_mfma<<<dim3(NPB/64), 256, 0, stream>>>((const unsigned short*)xb2,
                                                      attfrag + (size_t)l*4096, a_s, a_d);
        for (int cc = 0; cc < 2; ++cc) {
            int node0 = cc * CHUNK;
            k_agg_y<<<dim3(CHUNK/4), 256, 0, stream>>>(rowptr, colx, a_s, a_d, xb2, y2, node0);
            k_gemm_ln<<<dim3(CHUNK/64), 512, 0, stream>>>((const unsigned short*)y2,
                                                          M2t + (size_t)l*DD*HD, bias2 + l*DD,
                                                          gam, bet, X, out,
                                                          (unsigned int*)xb2, node0);
        }
    }
}

// Round 5
// 573.240 us; speedup vs baseline: 4.4782x; 1.2265x over previous
//
#include <hip/hip_runtime.h>
#include <hip/hip_bf16.h>

#define BB 8
#define NN 4096
#define EE 131072          // edges per graph
#define ENL (EE + NN)      // + self loops
#define DD 256
#define HH 8
#define HD 2048
#define NPB (BB * NN)      // 32768 nodes total
#define CHUNK 16384        // nodes per y-chunk (4 graphs)
#define CAP 128            // bucket capacity per node (deg max ~56)

typedef __attribute__((ext_vector_type(8))) short bf16x8;
typedef __attribute__((ext_vector_type(4))) float f32x4;

static __device__ __forceinline__ float bf_lo(unsigned int u) { return __uint_as_float(u << 16); }
static __device__ __forceinline__ float bf_hi(unsigned int u) { return __uint_as_float(u & 0xFFFF0000u); }
static __device__ __forceinline__ unsigned short f2bf(float f) {
    __hip_bfloat16 h = __float2bfloat16(f);
    return *reinterpret_cast<unsigned short*>(&h);
}
static __device__ __forceinline__ unsigned int pack2(float a, float b) {
    return ((unsigned)f2bf(b) << 16) | f2bf(a);
}
static __device__ __forceinline__ void load_lds16(const void* g, void* l) {
    __builtin_amdgcn_global_load_lds(
        (const __attribute__((address_space(1))) unsigned int*)(g),
        (__attribute__((address_space(3))) unsigned int*)(l), 16, 0, 0);
}
static __device__ __forceinline__ float rl_f(float v, int lane) {
    return __uint_as_float(__builtin_amdgcn_readlane(__float_as_uint(v), lane));
}

// ---------- edge bucketing (replaces count+scan+scatter CSR build) ----------
__global__ void k_scatter(const int* __restrict__ edges, int* __restrict__ cnt, int* __restrict__ col) {
    int b = blockIdx.y;
    int idx = blockIdx.x * 256 + threadIdx.x;
    if (idx >= ENL) return;
    int src, dst;
    if (idx < EE) { src = edges[b*2*EE + idx]; dst = edges[b*2*EE + EE + idx]; }
    else { src = dst = idx - EE; }
    int g = b * NN + dst;
    int pos = atomicAdd(&cnt[g], 1);
    if (pos < CAP) col[(size_t)g * CAP + pos] = src;
}

// ---------- prep kernel A: M2t (blocks 0..511) + wsatt/wdatt (blocks 512..575) ----------
// M2t[l][c][h*256+d] = sum_o linW[l][c][h*256+o] * W[l][h*256+o][d]   (bf16)
// wsatt[l][h][k]     = sum_d att_src[l][h][d] * W[l][h*256+d][k]
__global__ __launch_bounds__(256) void k_prepA(const float* __restrict__ W, const float* __restrict__ linW,
                                               unsigned short* __restrict__ M2t,
                                               const float* __restrict__ asrc, const float* __restrict__ adst,
                                               float* __restrict__ wsatt, float* __restrict__ wdatt) {
    __shared__ float red[2][4][64];
    int bx = blockIdx.x;
    if (bx < 512) {
        // register-blocked: 8 c-rows per block, thread owns column d
        int cb = bx & 31, h = (bx >> 5) & 7, l = bx >> 8;
        int d = threadIdx.x;
        const float* Bp = W + ((size_t)l * HD + h * DD) * DD;               // [o][d]
        const float* Ap = linW + ((size_t)l * DD + cb * 8) * HD + h * DD;   // [c][o] stride HD
        float acc[8] = {};
        for (int o = 0; o < DD; ++o) {
            float w = Bp[(size_t)o * DD + d];
            #pragma unroll
            for (int c = 0; c < 8; ++c)
                acc[c] = fmaf(Ap[(size_t)c * HD + o], w, acc[c]);   // A idx thread-uniform -> s_load
        }
        #pragma unroll
        for (int c = 0; c < 8; ++c)
            M2t[((size_t)l * DD + cb * 8 + c) * HD + h * DD + d] = f2bf(acc[c]);
    } else {
        int idx = bx - 512;
        int kb = idx & 3, h = (idx >> 2) & 7, l = idx >> 5;
        int k = threadIdx.x & 63, dg = threadIdx.x >> 6;
        float accs = 0.f, accd = 0.f;
        #pragma unroll 4
        for (int dd = 0; dd < 64; ++dd) {
            int d = dg * 64 + dd;
            float w = W[((size_t)l * HD + h * DD + d) * DD + kb * 64 + k];
            accs = fmaf(asrc[(l*HH + h)*DD + d], w, accs);
            accd = fmaf(adst[(l*HH + h)*DD + d], w, accd);
        }
        red[0][dg][k] = accs; red[1][dg][k] = accd;
        __syncthreads();
        int t = threadIdx.x;
        if (t < 64)
            wsatt[(l*HH + h)*DD + kb*64 + t] = red[0][0][t] + red[0][1][t] + red[0][2][t] + red[0][3][t];
        else if (t < 128) {
            int kk = t - 64;
            wdatt[(l*HH + h)*DD + kb*64 + kk] = red[1][0][kk] + red[1][1][kk] + red[1][2][kk] + red[1][3][kk];
        }
    }
}

// ---------- prep kernel B: bias2 (blocks 0..127) + attfrag pack (blocks 128..131) ----------
__global__ __launch_bounds__(256) void k_prepB(const float* __restrict__ gbias, const float* __restrict__ linW,
                                               const float* __restrict__ linb, float* __restrict__ bias2,
                                               const float* __restrict__ ws, const float* __restrict__ wd,
                                               unsigned short* __restrict__ frag) {
    int bx = blockIdx.x;
    if (bx < 128) {
        int wv = threadIdx.x >> 6, lane = threadIdx.x & 63;
        int o = bx * 4 + wv;                  // 512 outputs: [l][c]
        int l = o >> 8, c = o & 255;
        const float4* g4 = (const float4*)(gbias + l * HD);
        const float4* w4 = (const float4*)(linW + (size_t)l * DD * HD + (size_t)c * HD);
        float acc = 0.f;
        #pragma unroll
        for (int j = 0; j < 8; ++j) {
            float4 g = g4[j * 64 + lane]; float4 w = w4[j * 64 + lane];
            acc += g.x * w.x + g.y * w.y + g.z * w.z + g.w * w.w;
        }
        #pragma unroll
        for (int msk = 1; msk < 64; msk <<= 1) acc += __shfl_xor(acc, msk);
        if (lane == 0) bias2[o] = acc + linb[o];
    } else {
        int idx = bx - 128;
        int l = idx >> 1;
        int t = (idx & 1) * 256 + threadIdx.x;    // 512 frag slots per layer
        int ks = t >> 6, lane = t & 63, c = lane & 15, q = lane >> 4;
        #pragma unroll
        for (int j = 0; j < 8; ++j) {
            int k = ks * 32 + q * 8 + j;
            float v = (c < 8) ? ws[(l*HH + c)*DD + k] : wd[(l*HH + (c-8))*DD + k];
            frag[((size_t)l * 512 + t) * 8 + j] = f2bf(v);
        }
    }
}

// ---------- f32 -> bf16 row conversion ----------
__global__ void k_tobf(const float* __restrict__ X, uint2* __restrict__ xb2) {
    int idx = blockIdx.x * 256 + threadIdx.x;
    float4 v = *(const float4*)(X + (size_t)idx * 4);
    uint2 o; o.x = pack2(v.x, v.y); o.y = pack2(v.z, v.w);
    xb2[idx] = o;
}

// ---------- attention scores via MFMA: [N x 256] @ [256 x 16] ----------
__global__ __launch_bounds__(256) void k_attn_mfma(const unsigned short* __restrict__ xb,
                                                   const unsigned short* __restrict__ attfrag,
                                                   float* __restrict__ a_s, float* __restrict__ a_d) {
    int tid = threadIdx.x;
    int wv = tid >> 6, lane = tid & 63;
    int m0 = blockIdx.x * 64 + wv * 16;
    int c = lane & 15, q = lane >> 4;
    const unsigned short* arow = xb + (size_t)(m0 + c) * DD;
    f32x4 acc = (f32x4){0.f, 0.f, 0.f, 0.f};
    #pragma unroll
    for (int ks = 0; ks < 8; ++ks) {
        bf16x8 af = *(const bf16x8*)(arow + ks * 32 + q * 8);
        bf16x8 bf = *(const bf16x8*)(attfrag + (size_t)(ks * 64 + lane) * 8);
        acc = __builtin_amdgcn_mfma_f32_16x16x32_bf16(af, bf, acc, 0, 0, 0);
    }
    #pragma unroll
    for (int rg = 0; rg < 4; ++rg) {
        int row = m0 + q * 4 + rg;
        if (c < 8) a_s[row * 8 + c] = acc[rg];
        else       a_d[row * 8 + (c - 8)] = acc[rg];
    }
}

// ---------- aggregation of INPUT x per head: y[n,h,:] = sum alpha x[src] ----------
__global__ __launch_bounds__(256) void k_agg_y(const int* __restrict__ cnt, const int* __restrict__ col,
                                               const float* __restrict__ a_s, const float* __restrict__ a_d,
                                               const uint2* __restrict__ xb2, uint2* __restrict__ y2,
                                               int node0) {
    int wave = threadIdx.x >> 6, lane = threadIdx.x & 63;
    int blk = blockIdx.x;
    int xcd = blk & 7, q = blk >> 3;
    int gl = xcd >> 1;
    int sub = ((xcd & 1) << 9) | q;
    int g = node0 + gl * NN + sub * 4 + wave;
    int b = g >> 12;
    int re = cnt[g];
    const int* cl = col + (size_t)g * CAP;
    int gb = b * NN;
    int hl = lane & 7, slot = lane >> 3;
    float adh = a_d[(size_t)g * 8 + hl];
    float acc[8][4] = {};
    float sacc = 0.f;
    for (int e0 = 0; e0 < re; e0 += 8) {
        int e = e0 + slot;
        bool valid = e < re;
        int srcl = valid ? cl[e] : 0;
        float w = 0.f;
        if (valid) {
            float xs = a_s[(size_t)(gb + srcl) * 8 + hl] + adh;
            xs = (xs > 0.f) ? xs : 0.2f * xs;
            w = __expf(xs);           // no max-subtraction: scores bounded, safe in f32
        }
        sacc += w;
        if (e0 + 8 <= re) {
            #pragma unroll
            for (int i = 0; i < 8; ++i) {
                int s = __builtin_amdgcn_readlane(srcl, i * 8);   // SGPR gather base
                uint2 u = xb2[(size_t)(gb + s) * 64 + lane];
                float x0 = bf_lo(u.x), x1 = bf_hi(u.x), x2 = bf_lo(u.y), x3 = bf_hi(u.y);
                #pragma unroll
                for (int h = 0; h < 8; ++h) {
                    float wh = rl_f(w, i * 8 + h);                // SGPR multiplier
                    acc[h][0] = fmaf(wh, x0, acc[h][0]);
                    acc[h][1] = fmaf(wh, x1, acc[h][1]);
                    acc[h][2] = fmaf(wh, x2, acc[h][2]);
                    acc[h][3] = fmaf(wh, x3, acc[h][3]);
                }
            }
        } else {
            int cntl = re - e0;
            for (int i = 0; i < cntl; ++i) {
                int s = __builtin_amdgcn_readlane(srcl, i * 8);
                uint2 u = xb2[(size_t)(gb + s) * 64 + lane];
                float x0 = bf_lo(u.x), x1 = bf_hi(u.x), x2 = bf_lo(u.y), x3 = bf_hi(u.y);
                #pragma unroll
                for (int h = 0; h < 8; ++h) {
                    float wh = rl_f(w, i * 8 + h);
                    acc[h][0] = fmaf(wh, x0, acc[h][0]);
                    acc[h][1] = fmaf(wh, x1, acc[h][1]);
                    acc[h][2] = fmaf(wh, x2, acc[h][2]);
                    acc[h][3] = fmaf(wh, x3, acc[h][3]);
                }
            }
        }
    }
    sacc += __shfl_xor(sacc, 8);
    sacc += __shfl_xor(sacc, 16);
    sacc += __shfl_xor(sacc, 32);
    float rinv = 1.f / (sacc + 1e-16f);
    uint2* yr = y2 + (size_t)(g - node0) * 512 + lane;
    #pragma unroll
    for (int h = 0; h < 8; ++h) {
        float rh = rl_f(rinv, h);
        uint2 o;
        o.x = pack2(acc[h][0] * rh, acc[h][1] * rh);
        o.y = pack2(acc[h][2] * rh, acc[h][3] * rh);
        yr[h * 64] = o;
    }
}

// ---------- fused: y @ M2t^T (MFMA) -> +bias -> LN -> +res -> relu -> out + xb2 ----------
// tile 64(M) x 256(N), BK=128, 512 threads (8 waves, each 64M x 32N)
__global__ __launch_bounds__(512) void k_gemm_ln(const unsigned short* __restrict__ Yb,
                                                 const unsigned short* __restrict__ Bt,
                                                 const float* __restrict__ bias2,
                                                 const float* __restrict__ gamma,
                                                 const float* __restrict__ beta,
                                                 const float* __restrict__ res,
                                                 float* __restrict__ out,
                                                 unsigned int* __restrict__ xb,
                                                 int node0) {
    __shared__ char lds[81920];   // A 16KB @0, B 64KB @16384; epilogue scratch overlays A
    int tid = threadIdx.x;
    int wv = tid >> 6, lane = tid & 63;
    int m0 = blockIdx.x * 64;
    int c = lane & 15, q = lane >> 4;
    f32x4 acc[4][2];
    #pragma unroll
    for (int mf = 0; mf < 4; ++mf)
        #pragma unroll
        for (int nf = 0; nf < 2; ++nf) acc[mf][nf] = (f32x4){0.f, 0.f, 0.f, 0.f};

    for (int kt = 0; kt < HD; kt += 128) {
        #pragma unroll
        for (int it = 0; it < 2; ++it) {
            int ci = it * 512 + wv * 64 + lane;
            int row = ci >> 4, j = ci & 15, jp = j ^ (row & 15);
            load_lds16(Yb + (size_t)(m0 + row) * HD + kt + jp * 8, lds + it * 8192 + wv * 1024);
        }
        #pragma unroll
        for (int it = 0; it < 8; ++it) {
            int ci = it * 512 + wv * 64 + lane;
            int row = ci >> 4, j = ci & 15, jp = j ^ (row & 15);
            load_lds16(Bt + (size_t)row * HD + kt + jp * 8, lds + 16384 + it * 8192 + wv * 1024);
        }
        __syncthreads();
        #pragma unroll
        for (int ks = 0; ks < 4; ++ks) {
            int kb = ks * 64 + (q << 4);
            bf16x8 af[4], bfr[2];
            #pragma unroll
            for (int mf = 0; mf < 4; ++mf) {
                int r = mf * 16 + c;
                af[mf] = *(const bf16x8*)(lds + r * 256 + (kb ^ ((r & 15) << 4)));
            }
            #pragma unroll
            for (int nf = 0; nf < 2; ++nf) {
                int nr = wv * 32 + nf * 16 + c;
                bfr[nf] = *(const bf16x8*)(lds + 16384 + nr * 256 + (kb ^ ((nr & 15) << 4)));
            }
            #pragma unroll
            for (int mf = 0; mf < 4; ++mf)
                #pragma unroll
                for (int nf = 0; nf < 2; ++nf)
                    acc[mf][nf] = __builtin_amdgcn_mfma_f32_16x16x32_bf16(af[mf], bfr[nf], acc[mf][nf], 0, 0, 0);
        }
        __syncthreads();
    }

    float2* lnbuf = (float2*)lds;
    float2* musd  = (float2*)(lds + 4096);
    float b2[2], gmv[2], btv[2];
    #pragma unroll
    for (int nf = 0; nf < 2; ++nf) {
        int colx = wv * 32 + nf * 16 + c;
        b2[nf] = bias2[colx]; gmv[nf] = gamma[colx]; btv[nf] = beta[colx];
    }
    #pragma unroll
    for (int mf = 0; mf < 4; ++mf)
        #pragma unroll
        for (int nf = 0; nf < 2; ++nf)
            #pragma unroll
            for (int rg = 0; rg < 4; ++rg)
                acc[mf][nf][rg] += b2[nf];
    #pragma unroll
    for (int mf = 0; mf < 4; ++mf) {
        #pragma unroll
        for (int rg = 0; rg < 4; ++rg) {
            float s = 0.f, ss = 0.f;
            #pragma unroll
            for (int nf = 0; nf < 2; ++nf) { float v = acc[mf][nf][rg]; s += v; ss += v * v; }
            #pragma unroll
            for (int msk = 1; msk < 16; msk <<= 1) { s += __shfl_xor(s, msk); ss += __shfl_xor(ss, msk); }
            if (c == 0) lnbuf[(mf * 16 + q * 4 + rg) * 8 + wv] = make_float2(s, ss);
        }
    }
    __syncthreads();
    if (tid < 64) {
        float s = 0.f, ss = 0.f;
        #pragma unroll
        for (int w = 0; w < 8; ++w) { float2 p = lnbuf[tid * 8 + w]; s += p.x; ss += p.y; }
        float mu = s * (1.f / 256.f);
        float var = ss * (1.f / 256.f) - mu * mu;
        musd[tid] = make_float2(mu, rsqrtf(var + 1e-5f));
    }
    __syncthreads();
    #pragma unroll
    for (int mf = 0; mf < 4; ++mf) {
        #pragma unroll
        for (int rg = 0; rg < 4; ++rg) {
            int row = mf * 16 + q * 4 + rg;
            float2 ms = musd[row];
            size_t grow = (size_t)(node0 + m0 + row);
            #pragma unroll
            for (int nf = 0; nf < 2; ++nf) {
                int colx = wv * 32 + nf * 16 + c;
                float o = (acc[mf][nf][rg] - ms.x) * ms.y * gmv[nf] + btv[nf] + res[grow * DD + colx];
                o = fmaxf(o, 0.f);
                out[grow * DD + colx] = o;
                float nb = __shfl_xor(o, 1);
                if (!(c & 1)) xb[grow * 128 + (colx >> 1)] = pack2(o, nb);
            }
        }
    }
}

extern "C" void kernel_launch(void* const* d_in, const int* in_sizes, int n_in,
                              void* d_out, int out_size, void* d_ws, size_t ws_size,
                              hipStream_t stream) {
    const float* emb   = (const float*)d_in[0];
    const int*   edges = (const int*)d_in[1];
    const float* W     = (const float*)d_in[2];
    const float* asrc  = (const float*)d_in[3];
    const float* adst  = (const float*)d_in[4];
    const float* gbias = (const float*)d_in[5];
    const float* linW  = (const float*)d_in[6];
    const float* linb  = (const float*)d_in[7];
    const float* gam   = (const float*)d_in[8];
    const float* bet   = (const float*)d_in[9];
    float* out = (float*)d_out;

    // workspace layout (bytes), total ~105 MB
    char* ws = (char*)d_ws;
    uint2*          y2      = (uint2*)(ws + 0);                  // 67108864 (CHUNK x 2048 bf16)
    uint2*          xb2     = (uint2*)(ws + 67108864);           // 16777216 (NPB x 256 bf16)
    unsigned short* M2t     = (unsigned short*)(ws + 83886080);  // 2097152
    float*          wsatt   = (float*)(ws + 85983232);           // 16384
    float*          wdatt   = (float*)(ws + 85999616);           // 16384
    float*          bias2   = (float*)(ws + 86016000);           // 2048
    float*          a_s     = (float*)(ws + 86018048);           // 1048576
    float*          a_d     = (float*)(ws + 87066624);           // 1048576
    int*            cnt     = (int*)(ws + 88115200);             // 131072
    int*            colx    = (int*)(ws + 88246272);             // 16777216 (NPB x CAP)
    unsigned short* attfrag = (unsigned short*)(ws + 105023488); // 16384

    hipMemsetAsync(cnt, 0, NPB * sizeof(int), stream);
    k_scatter<<<dim3((ENL + 255) / 256, BB), 256, 0, stream>>>(edges, cnt, colx);
    k_prepA<<<dim3(576), 256, 0, stream>>>(W, linW, M2t, asrc, adst, wsatt, wdatt);
    k_prepB<<<dim3(132), 256, 0, stream>>>(gbias, linW, linb, bias2, wsatt, wdatt, attfrag);
    k_tobf<<<dim3(NPB * 64 / 256), 256, 0, stream>>>(emb, xb2);

    for (int l = 0; l < 2; ++l) {
        const float* X = (l == 0) ? emb : out;
        k_attn_mfma<<<dim3(NPB / 64), 256, 0, stream>>>((const unsigned short*)xb2,
                                                        attfrag + (size_t)l * 4096, a_s, a_d);
        for (int cc = 0; cc < 2; ++cc) {
            int node0 = cc * CHUNK;
            k_agg_y<<<dim3(CHUNK / 4), 256, 0, stream>>>(cnt, colx, a_s, a_d, xb2, y2, node0);
            k_gemm_ln<<<dim3(CHUNK / 64), 512, 0, stream>>>((const unsigned short*)y2,
                                                            M2t + (size_t)l * DD * HD, bias2 + l * DD,
                                                            gam, bet, X, out,
                                                            (unsigned int*)xb2, node0);
        }
    }
}

// Round 6
// 543.806 us; speedup vs baseline: 4.7206x; 1.0541x over previous
//
#include <hip/hip_runtime.h>
#include <hip/hip_bf16.h>

#define BB 8
#define NN 4096
#define EE 131072          // edges per graph
#define ENL (EE + NN)      // + self loops
#define DD 256
#define HH 8
#define HD 2048
#define NPB (BB * NN)      // 32768 nodes total
#define CHUNK 16384        // nodes per y-chunk (4 graphs)
#define CAP 128            // bucket capacity per node (deg max ~56)

typedef __attribute__((ext_vector_type(8))) short bf16x8;
typedef __attribute__((ext_vector_type(4))) float f32x4;

static __device__ __forceinline__ float bf_lo(unsigned int u) { return __uint_as_float(u << 16); }
static __device__ __forceinline__ float bf_hi(unsigned int u) { return __uint_as_float(u & 0xFFFF0000u); }
static __device__ __forceinline__ unsigned short f2bf(float f) {
    __hip_bfloat16 h = __float2bfloat16(f);
    return *reinterpret_cast<unsigned short*>(&h);
}
static __device__ __forceinline__ unsigned int pack2(float a, float b) {
    return ((unsigned)f2bf(b) << 16) | f2bf(a);
}
static __device__ __forceinline__ void load_lds16(const void* g, void* l) {
    __builtin_amdgcn_global_load_lds(
        (const __attribute__((address_space(1))) unsigned int*)(g),
        (__attribute__((address_space(3))) unsigned int*)(l), 16, 0, 0);
}
static __device__ __forceinline__ float rl_f(float v, int lane) {
    return __uint_as_float(__builtin_amdgcn_readlane(__float_as_uint(v), lane));
}

// ---------- edge bucketing ----------
__global__ void k_scatter(const int* __restrict__ edges, int* __restrict__ cnt, int* __restrict__ col) {
    int b = blockIdx.y;
    int idx = blockIdx.x * 256 + threadIdx.x;
    if (idx >= ENL) return;
    int src, dst;
    if (idx < EE) { src = edges[b*2*EE + idx]; dst = edges[b*2*EE + EE + idx]; }
    else { src = dst = idx - EE; }
    int g = b * NN + dst;
    int pos = atomicAdd(&cnt[g], 1);
    if (pos < CAP) col[(size_t)g * CAP + pos] = src;
}

// ---------- prep kernel A: M2t (blocks 0..511) + wsatt/wdatt (blocks 512..575) ----------
__global__ __launch_bounds__(256) void k_prepA(const float* __restrict__ W, const float* __restrict__ linW,
                                               unsigned short* __restrict__ M2t,
                                               const float* __restrict__ asrc, const float* __restrict__ adst,
                                               float* __restrict__ wsatt, float* __restrict__ wdatt) {
    __shared__ float red[2][4][64];
    int bx = blockIdx.x;
    if (bx < 512) {
        int cb = bx & 31, h = (bx >> 5) & 7, l = bx >> 8;
        int d = threadIdx.x;
        const float* Bp = W + ((size_t)l * HD + h * DD) * DD;
        const float* Ap = linW + ((size_t)l * DD + cb * 8) * HD + h * DD;
        float acc[8] = {};
        for (int o = 0; o < DD; ++o) {
            float w = Bp[(size_t)o * DD + d];
            #pragma unroll
            for (int c = 0; c < 8; ++c)
                acc[c] = fmaf(Ap[(size_t)c * HD + o], w, acc[c]);
        }
        #pragma unroll
        for (int c = 0; c < 8; ++c)
            M2t[((size_t)l * DD + cb * 8 + c) * HD + h * DD + d] = f2bf(acc[c]);
    } else {
        int idx = bx - 512;
        int kb = idx & 3, h = (idx >> 2) & 7, l = idx >> 5;
        int k = threadIdx.x & 63, dg = threadIdx.x >> 6;
        float accs = 0.f, accd = 0.f;
        #pragma unroll 4
        for (int dd = 0; dd < 64; ++dd) {
            int d = dg * 64 + dd;
            float w = W[((size_t)l * HD + h * DD + d) * DD + kb * 64 + k];
            accs = fmaf(asrc[(l*HH + h)*DD + d], w, accs);
            accd = fmaf(adst[(l*HH + h)*DD + d], w, accd);
        }
        red[0][dg][k] = accs; red[1][dg][k] = accd;
        __syncthreads();
        int t = threadIdx.x;
        if (t < 64)
            wsatt[(l*HH + h)*DD + kb*64 + t] = red[0][0][t] + red[0][1][t] + red[0][2][t] + red[0][3][t];
        else if (t < 128) {
            int kk = t - 64;
            wdatt[(l*HH + h)*DD + kb*64 + kk] = red[1][0][kk] + red[1][1][kk] + red[1][2][kk] + red[1][3][kk];
        }
    }
}

// ---------- prep kernel B: bias2 (blocks 0..127) + attfrag pack (blocks 128..131) ----------
__global__ __launch_bounds__(256) void k_prepB(const float* __restrict__ gbias, const float* __restrict__ linW,
                                               const float* __restrict__ linb, float* __restrict__ bias2,
                                               const float* __restrict__ ws, const float* __restrict__ wd,
                                               unsigned short* __restrict__ frag) {
    int bx = blockIdx.x;
    if (bx < 128) {
        int wv = threadIdx.x >> 6, lane = threadIdx.x & 63;
        int o = bx * 4 + wv;
        int l = o >> 8, c = o & 255;
        const float4* g4 = (const float4*)(gbias + l * HD);
        const float4* w4 = (const float4*)(linW + (size_t)l * DD * HD + (size_t)c * HD);
        float acc = 0.f;
        #pragma unroll
        for (int j = 0; j < 8; ++j) {
            float4 g = g4[j * 64 + lane]; float4 w = w4[j * 64 + lane];
            acc += g.x * w.x + g.y * w.y + g.z * w.z + g.w * w.w;
        }
        #pragma unroll
        for (int msk = 1; msk < 64; msk <<= 1) acc += __shfl_xor(acc, msk);
        if (lane == 0) bias2[o] = acc + linb[o];
    } else {
        int idx = bx - 128;
        int l = idx >> 1;
        int t = (idx & 1) * 256 + threadIdx.x;
        int ks = t >> 6, lane = t & 63, c = lane & 15, q = lane >> 4;
        #pragma unroll
        for (int j = 0; j < 8; ++j) {
            int k = ks * 32 + q * 8 + j;
            float v = (c < 8) ? ws[(l*HH + c)*DD + k] : wd[(l*HH + (c-8))*DD + k];
            frag[((size_t)l * 512 + t) * 8 + j] = f2bf(v);
        }
    }
}

// ---------- f32 -> bf16 row conversion ----------
__global__ void k_tobf(const float* __restrict__ X, uint2* __restrict__ xb2) {
    int idx = blockIdx.x * 256 + threadIdx.x;
    float4 v = *(const float4*)(X + (size_t)idx * 4);
    uint2 o; o.x = pack2(v.x, v.y); o.y = pack2(v.z, v.w);
    xb2[idx] = o;
}

// ---------- attention scores via MFMA: [N x 256] @ [256 x 16] ----------
__global__ __launch_bounds__(256) void k_attn_mfma(const unsigned short* __restrict__ xb,
                                                   const unsigned short* __restrict__ attfrag,
                                                   float* __restrict__ a_s, float* __restrict__ a_d) {
    int tid = threadIdx.x;
    int wv = tid >> 6, lane = tid & 63;
    int m0 = blockIdx.x * 64 + wv * 16;
    int c = lane & 15, q = lane >> 4;
    const unsigned short* arow = xb + (size_t)(m0 + c) * DD;
    f32x4 acc = (f32x4){0.f, 0.f, 0.f, 0.f};
    #pragma unroll
    for (int ks = 0; ks < 8; ++ks) {
        bf16x8 af = *(const bf16x8*)(arow + ks * 32 + q * 8);
        bf16x8 bf = *(const bf16x8*)(attfrag + (size_t)(ks * 64 + lane) * 8);
        acc = __builtin_amdgcn_mfma_f32_16x16x32_bf16(af, bf, acc, 0, 0, 0);
    }
    #pragma unroll
    for (int rg = 0; rg < 4; ++rg) {
        int row = m0 + q * 4 + rg;
        if (c < 8) a_s[row * 8 + c] = acc[rg];
        else       a_d[row * 8 + (c - 8)] = acc[rg];
    }
}

// ---------- aggregation of INPUT x per head: y[n,h,:] = sum alpha x[src] ----------
// ILP version: per 8-edge chunk, issue all 8 gathers before the weight math.
__global__ __launch_bounds__(256) void k_agg_y(const int* __restrict__ cnt, const int* __restrict__ col,
                                               const float* __restrict__ a_s, const float* __restrict__ a_d,
                                               const uint2* __restrict__ xb2, uint2* __restrict__ y2,
                                               int node0) {
    int wave = threadIdx.x >> 6, lane = threadIdx.x & 63;
    int blk = blockIdx.x;
    int xcd = blk & 7, q = blk >> 3;
    int gl = xcd >> 1;
    int sub = ((xcd & 1) << 9) | q;
    int g = node0 + gl * NN + sub * 4 + wave;
    int b = g >> 12;
    int re = cnt[g];
    const int* cl = col + (size_t)g * CAP;
    int gb = b * NN;
    int hl = lane & 7, slot = lane >> 3;
    float adh = a_d[(size_t)g * 8 + hl];
    float acc[8][4] = {};
    float sacc = 0.f;
    int nfull = re & ~7;
    for (int e0 = 0; e0 < nfull; e0 += 8) {
        int srcl = cl[e0 + slot];
        float sg = a_s[(size_t)(gb + srcl) * 8 + hl];          // score gather early
        int ss[8];
        #pragma unroll
        for (int i = 0; i < 8; ++i) ss[i] = __builtin_amdgcn_readlane(srcl, i * 8);
        uint2 u[8];
        #pragma unroll
        for (int i = 0; i < 8; ++i)
            u[i] = xb2[(size_t)(gb + ss[i]) * 64 + lane];      // 8 loads in flight
        float xs = sg + adh;
        xs = (xs > 0.f) ? xs : 0.2f * xs;
        float w = __expf(xs);                                   // scores bounded, safe in f32
        sacc += w;
        #pragma unroll
        for (int i = 0; i < 8; ++i) {
            float x0 = bf_lo(u[i].x), x1 = bf_hi(u[i].x), x2 = bf_lo(u[i].y), x3 = bf_hi(u[i].y);
            #pragma unroll
            for (int h = 0; h < 8; ++h) {
                float wh = rl_f(w, i * 8 + h);
                acc[h][0] = fmaf(wh, x0, acc[h][0]);
                acc[h][1] = fmaf(wh, x1, acc[h][1]);
                acc[h][2] = fmaf(wh, x2, acc[h][2]);
                acc[h][3] = fmaf(wh, x3, acc[h][3]);
            }
        }
    }
    if (nfull < re) {                                           // tail chunk (<8 edges)
        int e = nfull + slot;
        bool valid = e < re;
        int srcl = valid ? cl[e] : 0;
        float w = 0.f;
        if (valid) {
            float xs = a_s[(size_t)(gb + srcl) * 8 + hl] + adh;
            xs = (xs > 0.f) ? xs : 0.2f * xs;
            w = __expf(xs);
        }
        sacc += w;
        int cntl = re - nfull;
        for (int i = 0; i < cntl; ++i) {
            int s = __builtin_amdgcn_readlane(srcl, i * 8);
            uint2 u = xb2[(size_t)(gb + s) * 64 + lane];
            float x0 = bf_lo(u.x), x1 = bf_hi(u.x), x2 = bf_lo(u.y), x3 = bf_hi(u.y);
            #pragma unroll
            for (int h = 0; h < 8; ++h) {
                float wh = rl_f(w, i * 8 + h);
                acc[h][0] = fmaf(wh, x0, acc[h][0]);
                acc[h][1] = fmaf(wh, x1, acc[h][1]);
                acc[h][2] = fmaf(wh, x2, acc[h][2]);
                acc[h][3] = fmaf(wh, x3, acc[h][3]);
            }
        }
    }
    sacc += __shfl_xor(sacc, 8);
    sacc += __shfl_xor(sacc, 16);
    sacc += __shfl_xor(sacc, 32);
    float rinv = 1.f / (sacc + 1e-16f);
    uint2* yr = y2 + (size_t)(g - node0) * 512 + lane;
    #pragma unroll
    for (int h = 0; h < 8; ++h) {
        float rh = rl_f(rinv, h);
        uint2 o;
        o.x = pack2(acc[h][0] * rh, acc[h][1] * rh);
        o.y = pack2(acc[h][2] * rh, acc[h][3] * rh);
        yr[h * 64] = o;
    }
}

// ---------- fused: y @ M2t^T (MFMA, double-buffered) -> +bias -> LN -> +res -> relu ----------
// tile 64(M) x 256(N), BK=64, 512 threads (8 waves, each 64M x 32N), 2-phase pipeline
__global__ __launch_bounds__(512) void k_gemm_ln(const unsigned short* __restrict__ Yb,
                                                 const unsigned short* __restrict__ Bt,
                                                 const float* __restrict__ bias2,
                                                 const float* __restrict__ gamma,
                                                 const float* __restrict__ beta,
                                                 const float* __restrict__ res,
                                                 float* __restrict__ out,
                                                 unsigned int* __restrict__ xb,
                                                 int node0) {
    // buf0: A@0 (8KB) B@8192 (32KB); buf1: A@40960 B@49152; LN scratch @81920
    __shared__ char lds[86528];
    int tid = threadIdx.x;
    int wv = tid >> 6, lane = tid & 63;
    int m0 = blockIdx.x * 64;
    int c = lane & 15, q = lane >> 4;
    f32x4 acc[4][2];
    #pragma unroll
    for (int mf = 0; mf < 4; ++mf)
        #pragma unroll
        for (int nf = 0; nf < 2; ++nf) acc[mf][nf] = (f32x4){0.f, 0.f, 0.f, 0.f};

    // A-tile 64x64k: 512 16B-chunks (1/thread). B-tile 256x64k: 2048 chunks (4/thread).
    // linear LDS dest, pre-swizzled global source (chunk jp = j ^ (row&7))
    #define STAGE(BUF, KT) do {                                                        \
        int row_ = tid >> 3, j_ = tid & 7, jp_ = j_ ^ (row_ & 7);                      \
        load_lds16(Yb + (size_t)(m0 + row_) * HD + (KT) + jp_ * 8,                     \
                   lds + (BUF) * 40960 + wv * 1024);                                   \
        _Pragma("unroll")                                                              \
        for (int it_ = 0; it_ < 4; ++it_) {                                            \
            int ci_ = it_ * 512 + tid;                                                 \
            int br_ = ci_ >> 3, bj_ = ci_ & 7, bjp_ = bj_ ^ (br_ & 7);                 \
            load_lds16(Bt + (size_t)br_ * HD + (KT) + bjp_ * 8,                        \
                       lds + (BUF) * 40960 + 8192 + it_ * 8192 + wv * 1024);           \
        }                                                                              \
    } while (0)

    #define COMPUTE(BUF) do {                                                          \
        const char* Ab_ = lds + (BUF) * 40960;                                         \
        const char* Bb_ = lds + (BUF) * 40960 + 8192;                                  \
        _Pragma("unroll")                                                              \
        for (int ks = 0; ks < 2; ++ks) {                                               \
            int kb = ks * 64 + (q << 4);                                               \
            bf16x8 af[4], bfr[2];                                                      \
            _Pragma("unroll")                                                          \
            for (int mf = 0; mf < 4; ++mf) {                                           \
                int r = mf * 16 + c;                                                   \
                af[mf] = *(const bf16x8*)(Ab_ + r * 128 + (kb ^ ((r & 7) << 4)));      \
            }                                                                          \
            _Pragma("unroll")                                                          \
            for (int nf = 0; nf < 2; ++nf) {                                           \
                int nr = wv * 32 + nf * 16 + c;                                        \
                bfr[nf] = *(const bf16x8*)(Bb_ + nr * 128 + (kb ^ ((nr & 7) << 4)));   \
            }                                                                          \
            _Pragma("unroll")                                                          \
            for (int mf = 0; mf < 4; ++mf)                                             \
                _Pragma("unroll")                                                      \
                for (int nf = 0; nf < 2; ++nf)                                         \
                    acc[mf][nf] = __builtin_amdgcn_mfma_f32_16x16x32_bf16(             \
                        af[mf], bfr[nf], acc[mf][nf], 0, 0, 0);                        \
        }                                                                              \
    } while (0)

    STAGE(0, 0);
    __syncthreads();
    for (int t = 0; t < 32; t += 2) {
        if (t + 1 < 32) STAGE(1, (t + 1) * 64);   // issue next-tile loads BEFORE compute
        COMPUTE(0);
        __syncthreads();                           // implicit vmcnt(0): next tile ready
        if (t + 2 < 32) STAGE(0, (t + 2) * 64);
        COMPUTE(1);
        __syncthreads();
    }
    #undef STAGE
    #undef COMPUTE

    // ---- epilogue: +bias, LayerNorm (cross-wave via LDS), +res, relu, f32 + bf16 emit ----
    float2* lnbuf = (float2*)(lds + 81920);   // [64][8] float2 = 4KB
    float2* musd  = (float2*)(lds + 86016);   // [64] -- fits: 86528 total
    float b2[2], gmv[2], btv[2];
    #pragma unroll
    for (int nf = 0; nf < 2; ++nf) {
        int colx = wv * 32 + nf * 16 + c;
        b2[nf] = bias2[colx]; gmv[nf] = gamma[colx]; btv[nf] = beta[colx];
    }
    #pragma unroll
    for (int mf = 0; mf < 4; ++mf)
        #pragma unroll
        for (int nf = 0; nf < 2; ++nf)
            #pragma unroll
            for (int rg = 0; rg < 4; ++rg)
                acc[mf][nf][rg] += b2[nf];
    #pragma unroll
    for (int mf = 0; mf < 4; ++mf) {
        #pragma unroll
        for (int rg = 0; rg < 4; ++rg) {
            float s = 0.f, ss = 0.f;
            #pragma unroll
            for (int nf = 0; nf < 2; ++nf) { float v = acc[mf][nf][rg]; s += v; ss += v * v; }
            #pragma unroll
            for (int msk = 1; msk < 16; msk <<= 1) { s += __shfl_xor(s, msk); ss += __shfl_xor(ss, msk); }
            if (c == 0) lnbuf[(mf * 16 + q * 4 + rg) * 8 + wv] = make_float2(s, ss);
        }
    }
    __syncthreads();
    if (tid < 64) {
        float s = 0.f, ss = 0.f;
        #pragma unroll
        for (int w = 0; w < 8; ++w) { float2 p = lnbuf[tid * 8 + w]; s += p.x; ss += p.y; }
        float mu = s * (1.f / 256.f);
        float var = ss * (1.f / 256.f) - mu * mu;
        musd[tid] = make_float2(mu, rsqrtf(var + 1e-5f));
    }
    __syncthreads();
    #pragma unroll
    for (int mf = 0; mf < 4; ++mf) {
        #pragma unroll
        for (int rg = 0; rg < 4; ++rg) {
            int row = mf * 16 + q * 4 + rg;
            float2 ms = musd[row];
            size_t grow = (size_t)(node0 + m0 + row);
            #pragma unroll
            for (int nf = 0; nf < 2; ++nf) {
                int colx = wv * 32 + nf * 16 + c;
                float o = (acc[mf][nf][rg] - ms.x) * ms.y * gmv[nf] + btv[nf] + res[grow * DD + colx];
                o = fmaxf(o, 0.f);
                out[grow * DD + colx] = o;
                float nb = __shfl_xor(o, 1);
                if (!(c & 1)) xb[grow * 128 + (colx >> 1)] = pack2(o, nb);
            }
        }
    }
}

extern "C" void kernel_launch(void* const* d_in, const int* in_sizes, int n_in,
                              void* d_out, int out_size, void* d_ws, size_t ws_size,
                              hipStream_t stream) {
    const float* emb   = (const float*)d_in[0];
    const int*   edges = (const int*)d_in[1];
    const float* W     = (const float*)d_in[2];
    const float* asrc  = (const float*)d_in[3];
    const float* adst  = (const float*)d_in[4];
    const float* gbias = (const float*)d_in[5];
    const float* linW  = (const float*)d_in[6];
    const float* linb  = (const float*)d_in[7];
    const float* gam   = (const float*)d_in[8];
    const float* bet   = (const float*)d_in[9];
    float* out = (float*)d_out;

    // workspace layout (bytes), total ~105 MB
    char* ws = (char*)d_ws;
    uint2*          y2      = (uint2*)(ws + 0);                  // 67108864 (CHUNK x 2048 bf16)
    uint2*          xb2     = (uint2*)(ws + 67108864);           // 16777216 (NPB x 256 bf16)
    unsigned short* M2t     = (unsigned short*)(ws + 83886080);  // 2097152
    float*          wsatt   = (float*)(ws + 85983232);           // 16384
    float*          wdatt   = (float*)(ws + 85999616);           // 16384
    float*          bias2   = (float*)(ws + 86016000);           // 2048
    float*          a_s     = (float*)(ws + 86018048);           // 1048576
    float*          a_d     = (float*)(ws + 87066624);           // 1048576
    int*            cnt     = (int*)(ws + 88115200);             // 131072
    int*            colx    = (int*)(ws + 88246272);             // 16777216 (NPB x CAP)
    unsigned short* attfrag = (unsigned short*)(ws + 105023488); // 16384

    hipMemsetAsync(cnt, 0, NPB * sizeof(int), stream);
    k_scatter<<<dim3((ENL + 255) / 256, BB), 256, 0, stream>>>(edges, cnt, colx);
    k_prepA<<<dim3(576), 256, 0, stream>>>(W, linW, M2t, asrc, adst, wsatt, wdatt);
    k_prepB<<<dim3(132), 256, 0, stream>>>(gbias, linW, linb, bias2, wsatt, wdatt, attfrag);
    k_tobf<<<dim3(NPB * 64 / 256), 256, 0, stream>>>(emb, xb2);

    for (int l = 0; l < 2; ++l) {
        const float* X = (l == 0) ? emb : out;
        k_attn_mfma<<<dim3(NPB / 64), 256, 0, stream>>>((const unsigned short*)xb2,
                                                        attfrag + (size_t)l * 4096, a_s, a_d);
        for (int cc = 0; cc < 2; ++cc) {
            int node0 = cc * CHUNK;
            k_agg_y<<<dim3(CHUNK / 4), 256, 0, stream>>>(cnt, colx, a_s, a_d, xb2, y2, node0);
            k_gemm_ln<<<dim3(CHUNK / 64), 512, 0, stream>>>((const unsigned short*)y2,
                                                            M2t + (size_t)l * DD * HD, bias2 + l * DD,
                                                            gam, bet, X, out,
                                                            (unsigned int*)xb2, node0);
        }
    }
}